// Round 12
// baseline (397.066 us; speedup 1.0000x reference)
//
#include <hip/hip_runtime.h>
#include <hip/hip_bf16.h>
#include <hip/hip_cooperative_groups.h>
#include <math.h>

namespace cg = cooperative_groups;

#define S_LEN 2048
#define DM    1024
#define NH    16
#define DH    64
#define CHUNK 64
#define NCH   (S_LEN / CHUNK)          // 32
#define ST_STRIDE (DH * DH + DH)       // 4160 floats per (head,chunk) state

typedef __attribute__((ext_vector_type(8))) short bf16x8;   // 8 bf16 in 4 VGPRs
typedef __attribute__((ext_vector_type(4))) float f32x4;

__device__ __forceinline__ float softplus_f(float x) {
    // fast path: outputs are bf16-rounded downstream, 2-ulp transcendentals invisible
    return (x > 20.0f) ? x : __logf(1.0f + __expf(x));
}

__device__ __forceinline__ ushort bf16r(float f) {   // round-to-nearest-even f32 -> bf16
    union { float f; unsigned int u; } c; c.f = f;
    unsigned int u = c.u;
    u = (u + 0x7FFFu + ((u >> 16) & 1u)) >> 16;
    return (ushort)u;
}

__device__ __forceinline__ float b2f(ushort u) {     // bf16 -> f32 (shift)
    union { unsigned int i; float f; } c; c.i = ((unsigned int)u) << 16;
    return c.f;
}

// ---------------- fused cast: x (2 slabs) + 4 weights, one launch ----------------
__global__ __launch_bounds__(256)
void cast_all_kernel(const float* __restrict__ x,
                     const float* __restrict__ Wq, const float* __restrict__ Wk,
                     const float* __restrict__ Wv, const float* __restrict__ Wo,
                     ushort* __restrict__ x_bf, ushort* __restrict__ w_bf)
{
    const int y = blockIdx.y;          // 0,1: x halves; 2..5: Wq,Wk,Wv,Wo
    const float* src;
    ushort* dst;
    if (y < 2) { src = x + (size_t)y * (DM * DM);  dst = x_bf + (size_t)y * (DM * DM); }
    else {
        const float* ws[4] = {Wq, Wk, Wv, Wo};
        src = ws[y - 2];  dst = w_bf + (size_t)(y - 2) * (DM * DM);
    }
    const int i = (blockIdx.x * 256 + threadIdx.x) * 4;
    const float4 v = *(const float4*)(src + i);
    ushort4 o; o.x = bf16r(v.x); o.y = bf16r(v.y); o.z = bf16r(v.z); o.w = bf16r(v.w);
    *(ushort4*)(dst + i) = o;
}

// ============ QKV GEMM: BM=64 x BN=128, BK=64, 768 blocks (3/CU) — R9-proven, bf16 out ======
__global__ __launch_bounds__(256)
void qkv_gemm_kernel(const ushort* __restrict__ Xb, const ushort* __restrict__ Wqkv,
                     const float* __restrict__ bq, const float* __restrict__ bk,
                     const float* __restrict__ bv,
                     const float* __restrict__ beta,
                     ushort* __restrict__ qkv /* q|k|v contiguous, bf16 head layout */)
{
    __shared__ ushort Als[64 * 64];    // 8 KB
    __shared__ ushort Bls[128 * 64];   // 16 KB

    const int b = blockIdx.x;
    const int logical = (b & 7) * 96 + (b >> 3);      // XCD-bijective (768%8==0)
    const int mb = logical & 31, nb = logical >> 5;   // m-fastest within XCD
    const int m0 = mb * 64, n0 = nb * 128;
    const int z  = nb >> 3;                           // 0:q 1:k 2:v
    const int nz0 = (nb & 7) * 128;
    const float* bias = (z == 0) ? bq : (z == 1) ? bk : bv;

    const int t = threadIdx.x, w = t >> 6, l = t & 63;
    const int wr = w >> 1, wc = w & 1;                // 2x2 wave grid
    const int r8 = l >> 3;
    const int scol = ((l & 7) ^ r8) * 8;              // inverse-swizzled source col (elems)
    const int frow = l & 15, kq = l >> 4;

    f32x4 acc[2][4];
#pragma unroll
    for (int mi = 0; mi < 2; ++mi)
#pragma unroll
        for (int ni = 0; ni < 4; ++ni) acc[mi][ni] = (f32x4){0.f, 0.f, 0.f, 0.f};

    for (int kt = 0; kt < DM; kt += 64) {
#pragma unroll
        for (int k2 = 0; k2 < 6; ++k2) {
            const int idx = w + 4 * k2;
            if (idx < 8) {
                __builtin_amdgcn_global_load_lds(
                    (const __attribute__((address_space(1))) void*)(Xb + (size_t)(m0 + idx * 8 + r8) * DM + kt + scol),
                    (__attribute__((address_space(3))) void*)(Als + idx * 512), 16, 0, 0);
            } else {
                const int ib = idx - 8;
                __builtin_amdgcn_global_load_lds(
                    (const __attribute__((address_space(1))) void*)(Wqkv + (size_t)(n0 + ib * 8 + r8) * DM + kt + scol),
                    (__attribute__((address_space(3))) void*)(Bls + ib * 512), 16, 0, 0);
            }
        }
        __syncthreads();

#pragma unroll
        for (int ks = 0; ks < 2; ++ks) {
            bf16x8 af[2], bf[4];
#pragma unroll
            for (int mi = 0; mi < 2; ++mi) {
                const int rr = wr * 32 + mi * 16 + frow;
                af[mi] = *(const bf16x8*)&Als[rr * 64 + (((kq + 4 * ks) ^ (rr & 7)) << 3)];
            }
#pragma unroll
            for (int ni = 0; ni < 4; ++ni) {
                const int rr = wc * 64 + ni * 16 + frow;
                bf[ni] = *(const bf16x8*)&Bls[rr * 64 + (((kq + 4 * ks) ^ (rr & 7)) << 3)];
            }
#pragma unroll
            for (int mi = 0; mi < 2; ++mi)
#pragma unroll
                for (int ni = 0; ni < 4; ++ni)
                    acc[mi][ni] = __builtin_amdgcn_mfma_f32_16x16x32_bf16(af[mi], bf[ni], acc[mi][ni], 0, 0, 0);
        }
        __syncthreads();
    }

    ushort* outz = qkv + (size_t)z * (NH * S_LEN * DH);
    const int hwave = (nz0 + wc * 64) >> 6;           // wave-uniform head
    const float inv = (z < 2) ? (1.0f / (8.0f * __expf(beta[hwave]))) : 1.0f;
#pragma unroll
    for (int ni = 0; ni < 4; ++ni) {
        const int col = nz0 + wc * 64 + ni * 16 + (l & 15);
        const int d = col & 63;
        const float bcol = bias[col];
#pragma unroll
        for (int mi = 0; mi < 2; ++mi) {
            const int rbase = m0 + wr * 32 + mi * 16 + (l >> 4) * 4;
#pragma unroll
            for (int r = 0; r < 4; ++r) {
                float v = acc[mi][ni][r] + bcol;
                if (z < 2) v = softplus_f(v * inv);
                outz[((size_t)hwave * S_LEN + rbase + r) * DH + d] = bf16r(v);
            }
        }
    }
}

// ============ FUSED MIDDLE (cooperative): chunk_state^T -> scan -> attn_out -> o_gemm ======
// 512 blocks x 256 threads (2 blocks/CU -> all co-resident; grid.sync between phases).
// LDS: one 33KB arena aliased per phase (ph1: Ks/Vs f32 32KB; ph3: Vt/Ps bf16 16KB + den/rs;
// ph4: Als/Bls bf16 16KB).
__global__ __launch_bounds__(256)
void fused_mid_kernel(const ushort* __restrict__ q_ws, const ushort* __restrict__ k_ws,
                      const ushort* __restrict__ v_ws, float* __restrict__ st,
                      ushort* __restrict__ pfxT, ushort* __restrict__ op_bf,
                      const ushort* __restrict__ wo_bf, const float* __restrict__ bo,
                      float* __restrict__ out)
{
    __shared__ __align__(16) unsigned char smem[33 * 1024];
    cg::grid_group grid = cg::this_grid();

    const int blk = blockIdx.x;
    const int t = threadIdx.x;

    // ---------------- Phase 1: chunk state, TRANSPOSED  M^T[e][d] = sum_s V[s][e] K[s][d] ----
    {
        float* Ks = (float*)smem;             // [s][d] 16KB
        float* Vs = Ks + 64 * 64;             // [s][e] 16KB
        const int c = blk & 31, h = blk >> 5;
        const ushort* Kg = k_ws + ((size_t)h * S_LEN + c * CHUNK) * DH;
        const ushort* Vg = v_ws + ((size_t)h * S_LEN + c * CHUNK) * DH;
#pragma unroll
        for (int u = 0; u < 4; ++u) {
            int f = u * 256 + t;
            const ushort4 k4 = ((const ushort4*)Kg)[f];
            const ushort4 v4 = ((const ushort4*)Vg)[f];
            float* kp = Ks + f * 4;
            float* vp = Vs + f * 4;
            kp[0] = b2f(k4.x); kp[1] = b2f(k4.y); kp[2] = b2f(k4.z); kp[3] = b2f(k4.w);
            vp[0] = b2f(v4.x); vp[1] = b2f(v4.y); vp[2] = b2f(v4.z); vp[3] = b2f(v4.w);
        }
        __syncthreads();

        const int tx = t & 15, ty = t >> 4;   // ty -> e-block, tx -> d-block (transposed)
        float acc[4][4];
#pragma unroll
        for (int i = 0; i < 4; ++i)
#pragma unroll
            for (int j = 0; j < 4; ++j) acc[i][j] = 0.0f;

        for (int s = 0; s < 64; ++s) {
            const float4 ve = *(const float4*)&Vs[s * 64 + ty * 4];
            const float4 kd = *(const float4*)&Ks[s * 64 + tx * 4];
            const float vv[4] = {ve.x, ve.y, ve.z, ve.w};
            const float kv[4] = {kd.x, kd.y, kd.z, kd.w};
#pragma unroll
            for (int i = 0; i < 4; ++i)
#pragma unroll
                for (int j = 0; j < 4; ++j) acc[i][j] += vv[i] * kv[j];
        }
        float* base = st + (size_t)(h * NCH + c) * ST_STRIDE;
#pragma unroll
        for (int i = 0; i < 4; ++i) {
            float4 o; o.x = acc[i][0]; o.y = acc[i][1]; o.z = acc[i][2]; o.w = acc[i][3];
            *(float4*)(base + (ty * 4 + i) * 64 + tx * 4) = o;   // rows = e, cols = d
        }
        if (t < 64) {
            float s = 0.0f;
            for (int j = 0; j < 64; ++j) s += Ks[j * 64 + t];
            base[DH * DH + t] = s;                               // k1[d]
        }
    }
    __threadfence();
    grid.sync();

    // ---------------- Phase 2: exclusive prefix scan over chunks (+ bf16 copy, linear) ------
    {
        const int gid = blk * 256 + t;
        if (gid < NH * ST_STRIDE) {
            const int h = gid / ST_STRIDE;
            const int e = gid - h * ST_STRIDE;
            float* p = st + (size_t)h * NCH * ST_STRIDE + e;
            ushort* pt = pfxT + (size_t)h * NCH * ST_STRIDE + e;
            float acc = 0.0f;
            for (int c = 0; c < NCH; ++c) {
                const float v = p[(size_t)c * ST_STRIDE];
                p[(size_t)c * ST_STRIDE] = acc;
                pt[(size_t)c * ST_STRIDE] = bf16r(acc);   // coalesced: consecutive gid -> consecutive e
                acc += v;
            }
        }
    }
    __threadfence();
    grid.sync();

    // ---------------- Phase 3: attention output (MFMA) ----------------
    {
        ushort* Vt = (ushort*)smem;                       // [e][s] swizzled, 8KB
        ushort* Ps = Vt + 64 * 64;                        // [i][j] swizzled, 8KB
        float* denA = (float*)(smem + 16 * 1024);         // 256B
        float* rsA  = denA + 64;                          // 256B

        const int c = blk & 31, h = blk >> 5;
        const int w = t >> 6, l = t & 63;
        const int fr = l & 15, fg = l >> 4;
        const int iw0 = w * 16;
        const size_t cbase = ((size_t)h * S_LEN + c * CHUNK) * DH;
        const ushort* Qg = q_ws + cbase;
        const ushort* Kg = k_ws + cbase;
        const ushort* Vg = v_ws + cbase;
        const float*  pb = st   + (size_t)(h * NCH + c) * ST_STRIDE;
        const ushort* pT = pfxT + (size_t)(h * NCH + c) * ST_STRIDE;

        // stage Vt = V^T (bf16, swizzled)
        {
            const int s = t >> 2, e0 = (t & 3) * 16;
            ushort vv[16];
            *(ushort4*)(vv + 0)  = *(const ushort4*)(Vg + s * 64 + e0);
            *(ushort4*)(vv + 4)  = *(const ushort4*)(Vg + s * 64 + e0 + 4);
            *(ushort4*)(vv + 8)  = *(const ushort4*)(Vg + s * 64 + e0 + 8);
            *(ushort4*)(vv + 12) = *(const ushort4*)(Vg + s * 64 + e0 + 12);
#pragma unroll
            for (int ee = 0; ee < 16; ++ee) {
                const int e = e0 + ee;
                Vt[e * 64 + ((((s >> 3) ^ (e & 7)) << 3) | (s & 7))] = vv[ee];
            }
        }

        // S = Q K^T
        bf16x8 qf[2], kf0, kf1;
#pragma unroll
        for (int kh = 0; kh < 2; ++kh)
            qf[kh] = *(const bf16x8*)(Qg + (iw0 + fr) * 64 + kh * 32 + fg * 8);

        f32x4 sacc[4];
#pragma unroll
        for (int jn = 0; jn < 4; ++jn) sacc[jn] = (f32x4){0.f, 0.f, 0.f, 0.f};
#pragma unroll
        for (int jn = 0; jn < 4; ++jn) {
            kf0 = *(const bf16x8*)(Kg + (jn * 16 + fr) * 64 + fg * 8);
            kf1 = *(const bf16x8*)(Kg + (jn * 16 + fr) * 64 + 32 + fg * 8);
            sacc[jn] = __builtin_amdgcn_mfma_f32_16x16x32_bf16(qf[0], kf0, sacc[jn], 0, 0, 0);
            sacc[jn] = __builtin_amdgcn_mfma_f32_16x16x32_bf16(qf[1], kf1, sacc[jn], 0, 0, 0);
        }

        // mask, rowsum, P -> bf16 swizzled LDS
        float pr0 = 0.f, pr1 = 0.f, pr2 = 0.f, pr3 = 0.f;
#pragma unroll
        for (int jn = 0; jn < 4; ++jn) {
            const int j = jn * 16 + fr;
            const int gj = (jn * 2 + (fr >> 3));
#pragma unroll
            for (int r = 0; r < 4; ++r) {
                const int i = iw0 + fg * 4 + r;
                const float v = (j <= i) ? sacc[jn][r] : 0.0f;
                if (r == 0) pr0 += v; else if (r == 1) pr1 += v;
                else if (r == 2) pr2 += v; else pr3 += v;
                Ps[i * 64 + (((gj ^ (i & 7)) << 3) | (fr & 7))] = bf16r(v);
            }
        }
#pragma unroll
        for (int d = 1; d < 16; d <<= 1) {
            pr0 += __shfl_xor(pr0, d, 64);
            pr1 += __shfl_xor(pr1, d, 64);
            pr2 += __shfl_xor(pr2, d, 64);
            pr3 += __shfl_xor(pr3, d, 64);
        }
        if (fr == 0)      rsA[iw0 + fg * 4 + 0] = pr0;
        else if (fr == 1) rsA[iw0 + fg * 4 + 1] = pr1;
        else if (fr == 2) rsA[iw0 + fg * 4 + 2] = pr2;
        else if (fr == 3) rsA[iw0 + fg * 4 + 3] = pr3;

        // den_inter = Q . k1p (fp32)
        float den = 0.f;
#pragma unroll
        for (int kh = 0; kh < 2; ++kh)
#pragma unroll
            for (int jj = 0; jj < 8; ++jj)
                den += b2f((ushort)qf[kh][jj]) * pb[DH * DH + kh * 32 + fg * 8 + jj];
        den += __shfl_xor(den, 16, 64);
        den += __shfl_xor(den, 32, 64);
        if (l < 16) denA[iw0 + l] = den;

        __syncthreads();   // Vt / Ps / denA / rsA complete

        // O = P.V + Q.KVp^T
        bf16x8 paf[2];
#pragma unroll
        for (int kh = 0; kh < 2; ++kh)
            paf[kh] = *(const bf16x8*)&Ps[(iw0 + fr) * 64 + ((((kh * 4 + fg) ^ (fr & 7))) << 3)];

        f32x4 oacc[4];
#pragma unroll
        for (int jn = 0; jn < 4; ++jn) oacc[jn] = (f32x4){0.f, 0.f, 0.f, 0.f};
#pragma unroll
        for (int jn = 0; jn < 4; ++jn) {
            const int er = jn * 16 + fr;
            const bf16x8 vt0 = *(const bf16x8*)&Vt[er * 64 + ((((0 + fg) ^ (fr & 7))) << 3)];
            const bf16x8 vt1 = *(const bf16x8*)&Vt[er * 64 + ((((4 + fg) ^ (fr & 7))) << 3)];
            const bf16x8 tf0 = *(const bf16x8*)(pT + er * 64 + fg * 8);
            const bf16x8 tf1 = *(const bf16x8*)(pT + er * 64 + 32 + fg * 8);
            oacc[jn] = __builtin_amdgcn_mfma_f32_16x16x32_bf16(paf[0], vt0, oacc[jn], 0, 0, 0);
            oacc[jn] = __builtin_amdgcn_mfma_f32_16x16x32_bf16(paf[1], vt1, oacc[jn], 0, 0, 0);
            oacc[jn] = __builtin_amdgcn_mfma_f32_16x16x32_bf16(qf[0], tf0, oacc[jn], 0, 0, 0);
            oacc[jn] = __builtin_amdgcn_mfma_f32_16x16x32_bf16(qf[1], tf1, oacc[jn], 0, 0, 0);
        }

#pragma unroll
        for (int r = 0; r < 4; ++r) {
            const int i = iw0 + fg * 4 + r;
            const float rcp = 1.0f / (denA[i] + rsA[i]);
            const size_t rowb = (size_t)(c * CHUNK + i) * DM + h * DH;
#pragma unroll
            for (int jn = 0; jn < 4; ++jn)
                out_pre_store: op_bf[rowb + jn * 16 + fr] = bf16r(oacc[jn][r] * rcp);
        }
    }
    __threadfence();
    grid.sync();

    // ---------------- Phase 4: O projection  out = op_bf @ Wo^T + bo ----------------
    {
        ushort* Als = (ushort*)smem;          // 8KB
        ushort* Bls = Als + 64 * 64;          // 8KB

        const int logical = (blk & 7) * 64 + (blk >> 3);   // XCD-bijective (512%8==0)
        const int mb = logical & 31, nb = logical >> 5;
        const int m0 = mb * 64, n0 = nb * 64;

        const int w = t >> 6, l = t & 63;
        const int wr = w >> 1, wc = w & 1;
        const int r8 = l >> 3;
        const int scol = ((l & 7) ^ r8) * 8;
        const int frow = l & 15, kq = l >> 4;

        f32x4 acc[2][2];
#pragma unroll
        for (int mi = 0; mi < 2; ++mi)
#pragma unroll
            for (int ni = 0; ni < 2; ++ni) acc[mi][ni] = (f32x4){0.f, 0.f, 0.f, 0.f};

        for (int kt = 0; kt < DM; kt += 64) {
            __syncthreads();   // arena reuse across K-steps (also protects vs phase-3 reads: grid.sync above)
#pragma unroll
            for (int k2 = 0; k2 < 4; ++k2) {
                const int idx = w + 4 * k2;
                if (idx < 8) {
                    __builtin_amdgcn_global_load_lds(
                        (const __attribute__((address_space(1))) void*)(op_bf + (size_t)(m0 + idx * 8 + r8) * DM + kt + scol),
                        (__attribute__((address_space(3))) void*)(Als + idx * 512), 16, 0, 0);
                } else {
                    const int ib = idx - 8;
                    __builtin_amdgcn_global_load_lds(
                        (const __attribute__((address_space(1))) void*)(wo_bf + (size_t)(n0 + ib * 8 + r8) * DM + kt + scol),
                        (__attribute__((address_space(3))) void*)(Bls + ib * 512), 16, 0, 0);
                }
            }
            __syncthreads();

#pragma unroll
            for (int ks = 0; ks < 2; ++ks) {
                bf16x8 af[2], bf[2];
#pragma unroll
                for (int mi = 0; mi < 2; ++mi) {
                    const int rr = wr * 32 + mi * 16 + frow;
                    af[mi] = *(const bf16x8*)&Als[rr * 64 + (((kq + 4 * ks) ^ (rr & 7)) << 3)];
                }
#pragma unroll
                for (int ni = 0; ni < 2; ++ni) {
                    const int rr = wc * 32 + ni * 16 + frow;
                    bf[ni] = *(const bf16x8*)&Bls[rr * 64 + (((kq + 4 * ks) ^ (rr & 7)) << 3)];
                }
#pragma unroll
                for (int mi = 0; mi < 2; ++mi)
#pragma unroll
                    for (int ni = 0; ni < 2; ++ni)
                        acc[mi][ni] = __builtin_amdgcn_mfma_f32_16x16x32_bf16(af[mi], bf[ni], acc[mi][ni], 0, 0, 0);
            }
        }

#pragma unroll
        for (int ni = 0; ni < 2; ++ni) {
            const int col = n0 + wc * 32 + ni * 16 + (l & 15);
            const float bcol = bo[col];
#pragma unroll
            for (int mi = 0; mi < 2; ++mi) {
                const int rbase = m0 + wr * 32 + mi * 16 + (l >> 4) * 4;
#pragma unroll
                for (int r = 0; r < 4; ++r)
                    out[(size_t)(rbase + r) * DM + col] = acc[mi][ni][r] + bcol;
            }
        }
    }
}

extern "C" void kernel_launch(void* const* d_in, const int* in_sizes, int n_in,
                              void* d_out, int out_size, void* d_ws, size_t ws_size,
                              hipStream_t stream)
{
    const float* x    = (const float*)d_in[0];
    const float* Wq   = (const float*)d_in[1];
    const float* bq   = (const float*)d_in[2];
    const float* Wk   = (const float*)d_in[3];
    const float* bk   = (const float*)d_in[4];
    const float* Wv   = (const float*)d_in[5];
    const float* bv   = (const float*)d_in[6];
    const float* Wo   = (const float*)d_in[7];
    const float* bo   = (const float*)d_in[8];
    const float* beta = (const float*)d_in[9];
    float* out = (float*)d_out;

    // workspace layout
    ushort* q_ws  = (ushort*)d_ws;                                 // 3 x 2M bf16 (q|k|v)
    ushort* k_ws  = q_ws + (size_t)NH * S_LEN * DH;
    ushort* v_ws  = k_ws + (size_t)NH * S_LEN * DH;
    float*  st    = (float*)(v_ws + (size_t)NH * S_LEN * DH);      // 16*32*4160 f32
    ushort* x_bf  = (ushort*)(st + (size_t)NH * NCH * ST_STRIDE);  // 2M bf16
    ushort* w_bf  = x_bf + (size_t)S_LEN * DM;                     // 4 x 1M bf16
    ushort* op_bf = w_bf + (size_t)4 * DM * DM;                    // 2M bf16
    ushort* pfxT  = op_bf + (size_t)S_LEN * DM;                    // 16*32*4160 bf16

    const ushort* wo_bf = w_bf + (size_t)3 * DM * DM;

    cast_all_kernel<<<dim3((DM * DM) / 1024, 6), 256, 0, stream>>>(x, Wq, Wk, Wv, Wo, x_bf, w_bf);

    qkv_gemm_kernel<<<768, 256, 0, stream>>>(x_bf, w_bf, bq, bk, bv, beta, q_ws);

    {
        const ushort* q_c = q_ws; const ushort* k_c = k_ws; const ushort* v_c = v_ws;
        float* st_p = st; ushort* pfxT_p = pfxT; ushort* op_p = op_bf;
        const ushort* wo_c = wo_bf; const float* bo_c = bo; float* out_p = out;
        void* args[] = {&q_c, &k_c, &v_c, &st_p, &pfxT_p, &op_p, &wo_c, &bo_c, &out_p};
        hipLaunchCooperativeKernel((const void*)fused_mid_kernel, dim3(512), dim3(256),
                                   args, 0, stream);
    }
}

// Round 13
// 66.270 us; speedup vs baseline: 5.9916x; 5.9916x over previous
//
#include <hip/hip_runtime.h>
#include <hip/hip_bf16.h>
#include <math.h>

#define S_LEN 2048
#define DM    1024
#define NH    16
#define DH    64
#define CHUNK 64
#define NCH   (S_LEN / CHUNK)          // 32
#define ST_STRIDE (DH * DH + DH)       // 4160 elems per (head,chunk) state

typedef __attribute__((ext_vector_type(8))) short bf16x8;   // 8 bf16 in 4 VGPRs
typedef __attribute__((ext_vector_type(4))) float f32x4;

__device__ __forceinline__ float softplus_f(float x) {
    // fast path: outputs are bf16-rounded downstream (R12: absmax unchanged)
    return (x > 20.0f) ? x : __logf(1.0f + __expf(x));
}

__device__ __forceinline__ ushort bf16r(float f) {   // round-to-nearest-even f32 -> bf16
    union { float f; unsigned int u; } c; c.f = f;
    unsigned int u = c.u;
    u = (u + 0x7FFFu + ((u >> 16) & 1u)) >> 16;
    return (ushort)u;
}

__device__ __forceinline__ float b2f(ushort u) {     // bf16 -> f32 (shift)
    union { unsigned int i; float f; } c; c.i = ((unsigned int)u) << 16;
    return c.f;
}

// ---------------- fused cast: x (2 slabs) + 4 weights, one launch ----------------
__global__ __launch_bounds__(256)
void cast_all_kernel(const float* __restrict__ x,
                     const float* __restrict__ Wq, const float* __restrict__ Wk,
                     const float* __restrict__ Wv, const float* __restrict__ Wo,
                     ushort* __restrict__ x_bf, ushort* __restrict__ w_bf)
{
    const int y = blockIdx.y;          // 0,1: x halves; 2..5: Wq,Wk,Wv,Wo
    const float* src;
    ushort* dst;
    if (y < 2) { src = x + (size_t)y * (DM * DM);  dst = x_bf + (size_t)y * (DM * DM); }
    else {
        const float* ws[4] = {Wq, Wk, Wv, Wo};
        src = ws[y - 2];  dst = w_bf + (size_t)(y - 2) * (DM * DM);
    }
    const int i = (blockIdx.x * 256 + threadIdx.x) * 4;
    const float4 v = *(const float4*)(src + i);
    ushort4 o; o.x = bf16r(v.x); o.y = bf16r(v.y); o.z = bf16r(v.z); o.w = bf16r(v.w);
    *(ushort4*)(dst + i) = o;
}

// ============ QKV GEMM: BM=64 x BN=128, BK=64, 768 blocks (3/CU) — R9-proven, bf16 out ======
// Swizzle (verified 0-conflict): 8-row 1KB chunks; row r's eight 16B granules permuted
// g_phys = g ^ (r&7); linear gload_lds dest + inverse-swizzled global source col (rule 21);
// fragment reads apply the same XOR.
__global__ __launch_bounds__(256)
void qkv_gemm_kernel(const ushort* __restrict__ Xb, const ushort* __restrict__ Wqkv,
                     const float* __restrict__ bq, const float* __restrict__ bk,
                     const float* __restrict__ bv,
                     const float* __restrict__ beta,
                     ushort* __restrict__ qkv /* q|k|v contiguous, bf16 head layout */)
{
    __shared__ ushort Als[64 * 64];    // 8 KB
    __shared__ ushort Bls[128 * 64];   // 16 KB

    const int b = blockIdx.x;
    const int logical = (b & 7) * 96 + (b >> 3);      // XCD-bijective (768%8==0)
    const int mb = logical & 31, nb = logical >> 5;   // m-fastest within XCD
    const int m0 = mb * 64, n0 = nb * 128;
    const int z  = nb >> 3;                           // 0:q 1:k 2:v
    const int nz0 = (nb & 7) * 128;
    const float* bias = (z == 0) ? bq : (z == 1) ? bk : bv;

    const int t = threadIdx.x, w = t >> 6, l = t & 63;
    const int wr = w >> 1, wc = w & 1;                // 2x2 wave grid
    const int r8 = l >> 3;
    const int scol = ((l & 7) ^ r8) * 8;              // inverse-swizzled source col (elems)
    const int frow = l & 15, kq = l >> 4;

    f32x4 acc[2][4];
#pragma unroll
    for (int mi = 0; mi < 2; ++mi)
#pragma unroll
        for (int ni = 0; ni < 4; ++ni) acc[mi][ni] = (f32x4){0.f, 0.f, 0.f, 0.f};

    for (int kt = 0; kt < DM; kt += 64) {
#pragma unroll
        for (int k2 = 0; k2 < 6; ++k2) {
            const int idx = w + 4 * k2;
            if (idx < 8) {
                __builtin_amdgcn_global_load_lds(
                    (const __attribute__((address_space(1))) void*)(Xb + (size_t)(m0 + idx * 8 + r8) * DM + kt + scol),
                    (__attribute__((address_space(3))) void*)(Als + idx * 512), 16, 0, 0);
            } else {
                const int ib = idx - 8;
                __builtin_amdgcn_global_load_lds(
                    (const __attribute__((address_space(1))) void*)(Wqkv + (size_t)(n0 + ib * 8 + r8) * DM + kt + scol),
                    (__attribute__((address_space(3))) void*)(Bls + ib * 512), 16, 0, 0);
            }
        }
        __syncthreads();

#pragma unroll
        for (int ks = 0; ks < 2; ++ks) {
            bf16x8 af[2], bf[4];
#pragma unroll
            for (int mi = 0; mi < 2; ++mi) {
                const int rr = wr * 32 + mi * 16 + frow;
                af[mi] = *(const bf16x8*)&Als[rr * 64 + (((kq + 4 * ks) ^ (rr & 7)) << 3)];
            }
#pragma unroll
            for (int ni = 0; ni < 4; ++ni) {
                const int rr = wc * 64 + ni * 16 + frow;
                bf[ni] = *(const bf16x8*)&Bls[rr * 64 + (((kq + 4 * ks) ^ (rr & 7)) << 3)];
            }
#pragma unroll
            for (int mi = 0; mi < 2; ++mi)
#pragma unroll
                for (int ni = 0; ni < 4; ++ni)
                    acc[mi][ni] = __builtin_amdgcn_mfma_f32_16x16x32_bf16(af[mi], bf[ni], acc[mi][ni], 0, 0, 0);
        }
        __syncthreads();
    }

    ushort* outz = qkv + (size_t)z * (NH * S_LEN * DH);
    const int hwave = (nz0 >> 6) + wc;                // wave-uniform head (2 heads per 128-col tile)
    const float inv = (z < 2) ? (1.0f / (8.0f * __expf(beta[hwave]))) : 1.0f;
#pragma unroll
    for (int ni = 0; ni < 4; ++ni) {
        const int col = nz0 + wc * 64 + ni * 16 + (l & 15);
        const int d = col & 63;
        const float bcol = bias[col];
#pragma unroll
        for (int mi = 0; mi < 2; ++mi) {
            const int rbase = m0 + wr * 32 + mi * 16 + (l >> 4) * 4;
#pragma unroll
            for (int r = 0; r < 4; ++r) {
                float v = acc[mi][ni][r] + bcol;
                if (z < 2) v = softplus_f(v * inv);
                outz[((size_t)hwave * S_LEN + rbase + r) * DH + d] = bf16r(v);
            }
        }
    }
}

// ============ O projection: LDS-staged, BK=64, 512 blocks (2/CU) ============
__global__ __launch_bounds__(256)
void o_gemm_kernel(const ushort* __restrict__ Ab, const ushort* __restrict__ Wob,
                   const float* __restrict__ bo, float* __restrict__ out)
{
    __shared__ ushort Als[64 * 64];    // 8 KB
    __shared__ ushort Bls[64 * 64];    // 8 KB

    const int b = blockIdx.x;
    const int logical = (b & 7) * 64 + (b >> 3);      // XCD-bijective (512%8==0)
    const int mb = logical & 31, nb = logical >> 5;   // 32 x 16 tiles
    const int m0 = mb * 64, n0 = nb * 64;

    const int t = threadIdx.x, w = t >> 6, l = t & 63;
    const int wr = w >> 1, wc = w & 1;
    const int r8 = l >> 3;
    const int scol = ((l & 7) ^ r8) * 8;
    const int frow = l & 15, kq = l >> 4;

    f32x4 acc[2][2];
#pragma unroll
    for (int mi = 0; mi < 2; ++mi)
#pragma unroll
        for (int ni = 0; ni < 2; ++ni) acc[mi][ni] = (f32x4){0.f, 0.f, 0.f, 0.f};

    for (int kt = 0; kt < DM; kt += 64) {
#pragma unroll
        for (int k2 = 0; k2 < 4; ++k2) {
            const int idx = w + 4 * k2;                // 0..15
            if (idx < 8) {
                __builtin_amdgcn_global_load_lds(
                    (const __attribute__((address_space(1))) void*)(Ab + (size_t)(m0 + idx * 8 + r8) * DM + kt + scol),
                    (__attribute__((address_space(3))) void*)(Als + idx * 512), 16, 0, 0);
            } else {
                const int ib = idx - 8;
                __builtin_amdgcn_global_load_lds(
                    (const __attribute__((address_space(1))) void*)(Wob + (size_t)(n0 + ib * 8 + r8) * DM + kt + scol),
                    (__attribute__((address_space(3))) void*)(Bls + ib * 512), 16, 0, 0);
            }
        }
        __syncthreads();

#pragma unroll
        for (int ks = 0; ks < 2; ++ks) {
            bf16x8 af[2], bf[2];
#pragma unroll
            for (int mi = 0; mi < 2; ++mi) {
                const int rr = wr * 32 + mi * 16 + frow;
                af[mi] = *(const bf16x8*)&Als[rr * 64 + (((kq + 4 * ks) ^ (rr & 7)) << 3)];
            }
#pragma unroll
            for (int ni = 0; ni < 2; ++ni) {
                const int rr = wc * 32 + ni * 16 + frow;
                bf[ni] = *(const bf16x8*)&Bls[rr * 64 + (((kq + 4 * ks) ^ (rr & 7)) << 3)];
            }
#pragma unroll
            for (int mi = 0; mi < 2; ++mi)
#pragma unroll
                for (int ni = 0; ni < 2; ++ni)
                    acc[mi][ni] = __builtin_amdgcn_mfma_f32_16x16x32_bf16(af[mi], bf[ni], acc[mi][ni], 0, 0, 0);
        }
        __syncthreads();
    }

#pragma unroll
    for (int ni = 0; ni < 2; ++ni) {
        const int col = n0 + wc * 32 + ni * 16 + (l & 15);
        const float bcol = bo[col];
#pragma unroll
        for (int mi = 0; mi < 2; ++mi) {
            const int rbase = m0 + wr * 32 + mi * 16 + (l >> 4) * 4;
#pragma unroll
            for (int r = 0; r < 4; ++r)
                out[(size_t)(rbase + r) * DM + col] = acc[mi][ni][r] + bcol;
        }
    }
}

// ------- Pass B: per (head, chunk) TRANSPOSED state  M^T[e][d] = sum_s V[s][e] K[s][d] -------
// (Transposed so the scan's bf16 prefix copy is a LINEAR coalesced write, and attn_out's
//  MFMA B-fragments read pfxT rows directly.)  k1[d] kept at tail (fp32 path for den).
__global__ __launch_bounds__(256)
void chunk_state_kernel(const ushort* __restrict__ k_ws, const ushort* __restrict__ v_ws,
                        float* __restrict__ st)
{
    __shared__ float Ks[64 * 64];   // [s][d]
    __shared__ float Vs[64 * 64];   // [s][e]
    const int c = blockIdx.x, h = blockIdx.y;
    const int t = threadIdx.x;
    const ushort* Kg = k_ws + ((size_t)h * S_LEN + c * CHUNK) * DH;
    const ushort* Vg = v_ws + ((size_t)h * S_LEN + c * CHUNK) * DH;
#pragma unroll
    for (int u = 0; u < 4; ++u) {
        int f = u * 256 + t;
        const ushort4 k4 = ((const ushort4*)Kg)[f];
        const ushort4 v4 = ((const ushort4*)Vg)[f];
        float* kp = Ks + f * 4;
        float* vp = Vs + f * 4;
        kp[0] = b2f(k4.x); kp[1] = b2f(k4.y); kp[2] = b2f(k4.z); kp[3] = b2f(k4.w);
        vp[0] = b2f(v4.x); vp[1] = b2f(v4.y); vp[2] = b2f(v4.z); vp[3] = b2f(v4.w);
    }
    __syncthreads();

    const int tx = t & 15, ty = t >> 4;      // ty -> e-block, tx -> d-block (transposed)
    float acc[4][4];
#pragma unroll
    for (int i = 0; i < 4; ++i)
#pragma unroll
        for (int j = 0; j < 4; ++j) acc[i][j] = 0.0f;

    for (int s = 0; s < 64; ++s) {
        const float4 ve = *(const float4*)&Vs[s * 64 + ty * 4];
        const float4 kd = *(const float4*)&Ks[s * 64 + tx * 4];
        const float vv[4] = {ve.x, ve.y, ve.z, ve.w};
        const float kv[4] = {kd.x, kd.y, kd.z, kd.w};
#pragma unroll
        for (int i = 0; i < 4; ++i)
#pragma unroll
            for (int j = 0; j < 4; ++j) acc[i][j] += vv[i] * kv[j];
    }
    float* base = st + (size_t)(h * NCH + c) * ST_STRIDE;
#pragma unroll
    for (int i = 0; i < 4; ++i) {
        float4 o; o.x = acc[i][0]; o.y = acc[i][1]; o.z = acc[i][2]; o.w = acc[i][3];
        *(float4*)(base + (ty * 4 + i) * 64 + tx * 4) = o;   // rows = e, cols = d
    }
    if (t < 64) {
        float s = 0.0f;
        for (int j = 0; j < 64; ++j) s += Ks[j * 64 + t];
        base[DH * DH + t] = s;                               // k1[d]
    }
}

// ---- Pass C: exclusive prefix scan over chunks; bf16 copy is now LINEAR (coalesced) ----
__global__ __launch_bounds__(64)
void scan_kernel(float* __restrict__ st, ushort* __restrict__ pfxT)
{
    const int h = blockIdx.y;
    const int e = blockIdx.x * 64 + threadIdx.x;   // [0, ST_STRIDE)
    float* p = st + (size_t)h * NCH * ST_STRIDE + e;
    ushort* pt = pfxT + (size_t)h * NCH * ST_STRIDE + e;
    float acc = 0.0f;
    for (int c = 0; c < NCH; ++c) {
        const float v = p[(size_t)c * ST_STRIDE];
        p[(size_t)c * ST_STRIDE] = acc;            // exclusive prefix (same-thread RAW safe)
        pt[(size_t)c * ST_STRIDE] = bf16r(acc);    // coalesced: consecutive threads -> consecutive e
        acc += v;
    }
}

// ---------------- Pass D: per (head, chunk) output — MFMA (R11-proven) ----------------
// S = Q K^T (frags straight from global bf16).  mask+rowsum in-register; P -> bf16 swizzled
// LDS.  O = P.V (Vt transposed+swizzled) + Q.KVp^T (pfxT rows = e, contiguous d).
// den = Q.k1p (fp32) + rowsum.  Swizzle: granule_phys = granule_log ^ (row&7).
__global__ __launch_bounds__(256)
void attn_out_kernel(const ushort* __restrict__ q_ws, const ushort* __restrict__ k_ws,
                     const ushort* __restrict__ v_ws, const float* __restrict__ pfx,
                     const ushort* __restrict__ pfxT, ushort* __restrict__ out_pre)
{
    __shared__ ushort Vt[64 * 64];     // [e][s] swizzled, 8 KB
    __shared__ ushort Ps[64 * 64];     // [i][j] swizzled, 8 KB
    __shared__ float denA[64];
    __shared__ float rsA[64];

    const int c = blockIdx.x, h = blockIdx.y;
    const int t = threadIdx.x, w = t >> 6, l = t & 63;
    const int fr = l & 15, fg = l >> 4;
    const int iw0 = w * 16;                         // wave's output row stripe
    const size_t cbase = ((size_t)h * S_LEN + c * CHUNK) * DH;
    const ushort* Qg = q_ws + cbase;
    const ushort* Kg = k_ws + cbase;
    const ushort* Vg = v_ws + cbase;
    const float*  pb = pfx  + (size_t)(h * NCH + c) * ST_STRIDE;
    const ushort* pT = pfxT + (size_t)(h * NCH + c) * ST_STRIDE;

    // stage Vt = V^T (bf16, swizzled)
    {
        const int s = t >> 2, e0 = (t & 3) * 16;
        ushort vv[16];
        *(ushort4*)(vv + 0)  = *(const ushort4*)(Vg + s * 64 + e0);
        *(ushort4*)(vv + 4)  = *(const ushort4*)(Vg + s * 64 + e0 + 4);
        *(ushort4*)(vv + 8)  = *(const ushort4*)(Vg + s * 64 + e0 + 8);
        *(ushort4*)(vv + 12) = *(const ushort4*)(Vg + s * 64 + e0 + 12);
#pragma unroll
        for (int ee = 0; ee < 16; ++ee) {
            const int e = e0 + ee;
            Vt[e * 64 + ((((s >> 3) ^ (e & 7)) << 3) | (s & 7))] = vv[ee];
        }
    }

    // S = Q K^T
    bf16x8 qf[2], kf0, kf1;
#pragma unroll
    for (int kh = 0; kh < 2; ++kh)
        qf[kh] = *(const bf16x8*)(Qg + (iw0 + fr) * 64 + kh * 32 + fg * 8);

    f32x4 sacc[4];
#pragma unroll
    for (int jn = 0; jn < 4; ++jn) sacc[jn] = (f32x4){0.f, 0.f, 0.f, 0.f};
#pragma unroll
    for (int jn = 0; jn < 4; ++jn) {
        kf0 = *(const bf16x8*)(Kg + (jn * 16 + fr) * 64 + fg * 8);
        kf1 = *(const bf16x8*)(Kg + (jn * 16 + fr) * 64 + 32 + fg * 8);
        sacc[jn] = __builtin_amdgcn_mfma_f32_16x16x32_bf16(qf[0], kf0, sacc[jn], 0, 0, 0);
        sacc[jn] = __builtin_amdgcn_mfma_f32_16x16x32_bf16(qf[1], kf1, sacc[jn], 0, 0, 0);
    }

    // mask, rowsum, P -> bf16 swizzled LDS
    float pr0 = 0.f, pr1 = 0.f, pr2 = 0.f, pr3 = 0.f;
#pragma unroll
    for (int jn = 0; jn < 4; ++jn) {
        const int j = jn * 16 + fr;
        const int gj = (jn * 2 + (fr >> 3));        // granule of j
#pragma unroll
        for (int r = 0; r < 4; ++r) {
            const int i = iw0 + fg * 4 + r;
            const float v = (j <= i) ? sacc[jn][r] : 0.0f;
            if (r == 0) pr0 += v; else if (r == 1) pr1 += v;
            else if (r == 2) pr2 += v; else pr3 += v;
            Ps[i * 64 + (((gj ^ (i & 7)) << 3) | (fr & 7))] = bf16r(v);
        }
    }
#pragma unroll
    for (int d = 1; d < 16; d <<= 1) {
        pr0 += __shfl_xor(pr0, d, 64);
        pr1 += __shfl_xor(pr1, d, 64);
        pr2 += __shfl_xor(pr2, d, 64);
        pr3 += __shfl_xor(pr3, d, 64);
    }
    if (fr == 0)      rsA[iw0 + fg * 4 + 0] = pr0;
    else if (fr == 1) rsA[iw0 + fg * 4 + 1] = pr1;
    else if (fr == 2) rsA[iw0 + fg * 4 + 2] = pr2;
    else if (fr == 3) rsA[iw0 + fg * 4 + 3] = pr3;

    // den_inter = Q . k1p (fp32)
    float den = 0.f;
#pragma unroll
    for (int kh = 0; kh < 2; ++kh)
#pragma unroll
        for (int jj = 0; jj < 8; ++jj)
            den += b2f((ushort)qf[kh][jj]) * pb[DH * DH + kh * 32 + fg * 8 + jj];
    den += __shfl_xor(den, 16, 64);
    den += __shfl_xor(den, 32, 64);
    if (l < 16) denA[iw0 + l] = den;

    __syncthreads();   // Vt / Ps / denA / rsA complete

    // O = P.V + Q.KVp^T
    bf16x8 paf[2];
#pragma unroll
    for (int kh = 0; kh < 2; ++kh)
        paf[kh] = *(const bf16x8*)&Ps[(iw0 + fr) * 64 + ((((kh * 4 + fg) ^ (fr & 7))) << 3)];

    f32x4 oacc[4];
#pragma unroll
    for (int jn = 0; jn < 4; ++jn) oacc[jn] = (f32x4){0.f, 0.f, 0.f, 0.f};
#pragma unroll
    for (int jn = 0; jn < 4; ++jn) {
        const int er = jn * 16 + fr;
        const bf16x8 vt0 = *(const bf16x8*)&Vt[er * 64 + ((((0 + fg) ^ (fr & 7))) << 3)];
        const bf16x8 vt1 = *(const bf16x8*)&Vt[er * 64 + ((((4 + fg) ^ (fr & 7))) << 3)];
        const bf16x8 tf0 = *(const bf16x8*)(pT + er * 64 + fg * 8);
        const bf16x8 tf1 = *(const bf16x8*)(pT + er * 64 + 32 + fg * 8);
        oacc[jn] = __builtin_amdgcn_mfma_f32_16x16x32_bf16(paf[0], vt0, oacc[jn], 0, 0, 0);
        oacc[jn] = __builtin_amdgcn_mfma_f32_16x16x32_bf16(paf[1], vt1, oacc[jn], 0, 0, 0);
        oacc[jn] = __builtin_amdgcn_mfma_f32_16x16x32_bf16(qf[0], tf0, oacc[jn], 0, 0, 0);
        oacc[jn] = __builtin_amdgcn_mfma_f32_16x16x32_bf16(qf[1], tf1, oacc[jn], 0, 0, 0);
    }

    // epilogue: divide by den, store bf16
#pragma unroll
    for (int r = 0; r < 4; ++r) {
        const int i = iw0 + fg * 4 + r;
        const float rcp = 1.0f / (denA[i] + rsA[i]);
        const size_t rowb = (size_t)(c * CHUNK + i) * DM + h * DH;
#pragma unroll
        for (int jn = 0; jn < 4; ++jn)
            out_pre[rowb + jn * 16 + fr] = bf16r(oacc[jn][r] * rcp);
    }
}

extern "C" void kernel_launch(void* const* d_in, const int* in_sizes, int n_in,
                              void* d_out, int out_size, void* d_ws, size_t ws_size,
                              hipStream_t stream)
{
    const float* x    = (const float*)d_in[0];
    const float* Wq   = (const float*)d_in[1];
    const float* bq   = (const float*)d_in[2];
    const float* Wk   = (const float*)d_in[3];
    const float* bk   = (const float*)d_in[4];
    const float* Wv   = (const float*)d_in[5];
    const float* bv   = (const float*)d_in[6];
    const float* Wo   = (const float*)d_in[7];
    const float* bo   = (const float*)d_in[8];
    const float* beta = (const float*)d_in[9];
    float* out = (float*)d_out;

    // workspace layout
    ushort* q_ws  = (ushort*)d_ws;                                 // 3 x 2M bf16 (q|k|v)
    ushort* k_ws  = q_ws + (size_t)NH * S_LEN * DH;
    ushort* v_ws  = k_ws + (size_t)NH * S_LEN * DH;
    float*  st    = (float*)(v_ws + (size_t)NH * S_LEN * DH);      // 16*32*4160 f32
    ushort* x_bf  = (ushort*)(st + (size_t)NH * NCH * ST_STRIDE);  // 2M bf16
    ushort* w_bf  = x_bf + (size_t)S_LEN * DM;                     // 4 x 1M bf16
    ushort* op_bf = w_bf + (size_t)4 * DM * DM;                    // 2M bf16
    ushort* pfxT  = op_bf + (size_t)S_LEN * DM;                    // 16*32*4160 bf16

    const ushort* wo_bf = w_bf + (size_t)3 * DM * DM;

    cast_all_kernel<<<dim3((DM * DM) / 1024, 6), 256, 0, stream>>>(x, Wq, Wk, Wv, Wo, x_bf, w_bf);

    qkv_gemm_kernel<<<768, 256, 0, stream>>>(x_bf, w_bf, bq, bk, bv, beta, q_ws);

    chunk_state_kernel<<<dim3(NCH, NH), 256, 0, stream>>>(k_ws, v_ws, st);
    scan_kernel<<<dim3(ST_STRIDE / 64, NH), 64, 0, stream>>>(st, pfxT);
    attn_out_kernel<<<dim3(NCH, NH), 256, 0, stream>>>(q_ws, k_ws, v_ws, st, pfxT, op_bf);

    o_gemm_kernel<<<512, 256, 0, stream>>>(op_bf, wo_bf, bo, out);
}

// Round 14
// 65.234 us; speedup vs baseline: 6.0868x; 1.0159x over previous
//
#include <hip/hip_runtime.h>
#include <hip/hip_bf16.h>
#include <math.h>

#define S_LEN 2048
#define DM    1024
#define NH    16
#define DH    64
#define CHUNK 64
#define NCH   (S_LEN / CHUNK)          // 32
#define ST_STRIDE (DH * DH + DH)       // 4160 elems per (head,chunk) state

typedef __attribute__((ext_vector_type(8))) short bf16x8;   // 8 bf16 in 4 VGPRs
typedef __attribute__((ext_vector_type(4))) float f32x4;

__device__ __forceinline__ float softplus_f(float x) {
    // fast transcendentals: outputs bf16-rounded downstream (R12/R13: absmax unchanged)
    return (x > 20.0f) ? x : __logf(1.0f + __expf(x));
}

__device__ __forceinline__ ushort bf16r(float f) {   // round-to-nearest-even f32 -> bf16
    union { float f; unsigned int u; } c; c.f = f;
    unsigned int u = c.u;
    u = (u + 0x7FFFu + ((u >> 16) & 1u)) >> 16;
    return (ushort)u;
}

__device__ __forceinline__ float b2f(ushort u) {     // bf16 -> f32 (shift)
    union { unsigned int i; float f; } c; c.i = ((unsigned int)u) << 16;
    return c.f;
}

// ---------------- fused cast: x (2 slabs) + 4 weights, one launch ----------------
__global__ __launch_bounds__(256)
void cast_all_kernel(const float* __restrict__ x,
                     const float* __restrict__ Wq, const float* __restrict__ Wk,
                     const float* __restrict__ Wv, const float* __restrict__ Wo,
                     ushort* __restrict__ x_bf, ushort* __restrict__ w_bf)
{
    const int y = blockIdx.y;          // 0,1: x halves; 2..5: Wq,Wk,Wv,Wo
    const float* src;
    ushort* dst;
    if (y < 2) { src = x + (size_t)y * (DM * DM);  dst = x_bf + (size_t)y * (DM * DM); }
    else {
        const float* ws[4] = {Wq, Wk, Wv, Wo};
        src = ws[y - 2];  dst = w_bf + (size_t)(y - 2) * (DM * DM);
    }
    const int i = (blockIdx.x * 256 + threadIdx.x) * 4;
    const float4 v = *(const float4*)(src + i);
    ushort4 o; o.x = bf16r(v.x); o.y = bf16r(v.y); o.z = bf16r(v.z); o.w = bf16r(v.w);
    *(ushort4*)(dst + i) = o;
}

// ============ QKV GEMM: BM=64 x BN=128, BK=128 -> 8 K-steps, 768 blocks (3/CU) ============
// R13 structure with barrier-step count halved again (R9 trend: steps 32->16 = -9%).
// LDS 48KB (A 16KB + B 32KB), single-buffered; 3 blocks/CU preserved (144KB <= 160KB).
// Swizzle: rows = 16 granules of 16B; granule_phys = granule_log ^ (row&7) (involution;
// linear gload_lds dest + inverse-swizzled global source col, rule 21; reads same XOR).
// Staging instr = 4 rows: (row&7) = (idx&1)*4 | (l>>4).
__global__ __launch_bounds__(256)
void qkv_gemm_kernel(const ushort* __restrict__ Xb, const ushort* __restrict__ Wqkv,
                     const float* __restrict__ bq, const float* __restrict__ bk,
                     const float* __restrict__ bv,
                     const float* __restrict__ beta,
                     ushort* __restrict__ qkv /* q|k|v contiguous, bf16 head layout */)
{
    __shared__ ushort Als[64 * 128];    // 16 KB
    __shared__ ushort Bls[128 * 128];   // 32 KB

    const int b = blockIdx.x;
    const int logical = (b & 7) * 96 + (b >> 3);      // XCD-bijective (768%8==0)
    const int mb = logical & 31, nb = logical >> 5;   // m-fastest within XCD
    const int m0 = mb * 64, n0 = nb * 128;
    const int z  = nb >> 3;                           // 0:q 1:k 2:v
    const int nz0 = (nb & 7) * 128;
    const float* bias = (z == 0) ? bq : (z == 1) ? bk : bv;

    const int t = threadIdx.x, w = t >> 6, l = t & 63;
    const int wr = w >> 1, wc = w & 1;                // 2x2 wave grid
    const int rsub = l >> 4;                          // row within 4-row staging instr
    const int frow = l & 15, kq = l >> 4;

    f32x4 acc[2][4];
#pragma unroll
    for (int mi = 0; mi < 2; ++mi)
#pragma unroll
        for (int ni = 0; ni < 4; ++ni) acc[mi][ni] = (f32x4){0.f, 0.f, 0.f, 0.f};

    for (int kt = 0; kt < DM; kt += 128) {
        // stage: 48 gload instrs (A: 16, B: 32), wave w handles instr w+4*k2
#pragma unroll
        for (int k2 = 0; k2 < 12; ++k2) {
            const int idx = w + 4 * k2;               // 0..47
            const int r8g = ((idx & 1) << 2) | rsub;  // (global row) & 7  (parity of idx-16 == idx)
            const int scol = (((l & 15) ^ r8g) << 3); // inverse-swizzled source col (elems)
            if (idx < 16) {                           // A rows idx*4 .. idx*4+3
                __builtin_amdgcn_global_load_lds(
                    (const __attribute__((address_space(1))) void*)(Xb + (size_t)(m0 + idx * 4 + rsub) * DM + kt + scol),
                    (__attribute__((address_space(3))) void*)(Als + idx * 512), 16, 0, 0);
            } else {                                  // B rows (idx-16)*4 ..
                const int ib = idx - 16;
                __builtin_amdgcn_global_load_lds(
                    (const __attribute__((address_space(1))) void*)(Wqkv + (size_t)(n0 + ib * 4 + rsub) * DM + kt + scol),
                    (__attribute__((address_space(3))) void*)(Bls + ib * 512), 16, 0, 0);
            }
        }
        __syncthreads();   // staged data visible

#pragma unroll
        for (int ks = 0; ks < 4; ++ks) {
            bf16x8 af[2], bf[4];
#pragma unroll
            for (int mi = 0; mi < 2; ++mi) {
                const int rr = wr * 32 + mi * 16 + frow;
                af[mi] = *(const bf16x8*)&Als[rr * 128 + (((ks * 4 + kq) ^ (rr & 7)) << 3)];
            }
#pragma unroll
            for (int ni = 0; ni < 4; ++ni) {
                const int rr = wc * 64 + ni * 16 + frow;
                bf[ni] = *(const bf16x8*)&Bls[rr * 128 + (((ks * 4 + kq) ^ (rr & 7)) << 3)];
            }
#pragma unroll
            for (int mi = 0; mi < 2; ++mi)
#pragma unroll
                for (int ni = 0; ni < 4; ++ni)
                    acc[mi][ni] = __builtin_amdgcn_mfma_f32_16x16x32_bf16(af[mi], bf[ni], acc[mi][ni], 0, 0, 0);
        }
        __syncthreads();   // protect LDS before next stage
    }

    ushort* outz = qkv + (size_t)z * (NH * S_LEN * DH);
    const int hwave = (nz0 >> 6) + wc;                // wave-uniform head (2 heads per 128-col tile)
    const float inv = (z < 2) ? (1.0f / (8.0f * __expf(beta[hwave]))) : 1.0f;
#pragma unroll
    for (int ni = 0; ni < 4; ++ni) {
        const int col = nz0 + wc * 64 + ni * 16 + (l & 15);
        const int d = col & 63;
        const float bcol = bias[col];
#pragma unroll
        for (int mi = 0; mi < 2; ++mi) {
            const int rbase = m0 + wr * 32 + mi * 16 + (l >> 4) * 4;
#pragma unroll
            for (int r = 0; r < 4; ++r) {
                float v = acc[mi][ni][r] + bcol;
                if (z < 2) v = softplus_f(v * inv);
                outz[((size_t)hwave * S_LEN + rbase + r) * DH + d] = bf16r(v);
            }
        }
    }
}

// ============ O projection: LDS-staged, BK=128 -> 8 K-steps, 512 blocks (2/CU) ============
__global__ __launch_bounds__(256)
void o_gemm_kernel(const ushort* __restrict__ Ab, const ushort* __restrict__ Wob,
                   const float* __restrict__ bo, float* __restrict__ out)
{
    __shared__ ushort Als[64 * 128];    // 16 KB
    __shared__ ushort Bls[64 * 128];    // 16 KB

    const int b = blockIdx.x;
    const int logical = (b & 7) * 64 + (b >> 3);      // XCD-bijective (512%8==0)
    const int mb = logical & 31, nb = logical >> 5;   // 32 x 16 tiles
    const int m0 = mb * 64, n0 = nb * 64;

    const int t = threadIdx.x, w = t >> 6, l = t & 63;
    const int wr = w >> 1, wc = w & 1;
    const int rsub = l >> 4;
    const int frow = l & 15, kq = l >> 4;

    f32x4 acc[2][2];
#pragma unroll
    for (int mi = 0; mi < 2; ++mi)
#pragma unroll
        for (int ni = 0; ni < 2; ++ni) acc[mi][ni] = (f32x4){0.f, 0.f, 0.f, 0.f};

    for (int kt = 0; kt < DM; kt += 128) {
        // stage: 32 gload instrs (A: 16, B: 16), wave w handles instr w+4*k2
#pragma unroll
        for (int k2 = 0; k2 < 8; ++k2) {
            const int idx = w + 4 * k2;               // 0..31
            const int r8g = ((idx & 1) << 2) | rsub;
            const int scol = (((l & 15) ^ r8g) << 3);
            if (idx < 16) {
                __builtin_amdgcn_global_load_lds(
                    (const __attribute__((address_space(1))) void*)(Ab + (size_t)(m0 + idx * 4 + rsub) * DM + kt + scol),
                    (__attribute__((address_space(3))) void*)(Als + idx * 512), 16, 0, 0);
            } else {
                const int ib = idx - 16;
                __builtin_amdgcn_global_load_lds(
                    (const __attribute__((address_space(1))) void*)(Wob + (size_t)(n0 + ib * 4 + rsub) * DM + kt + scol),
                    (__attribute__((address_space(3))) void*)(Bls + ib * 512), 16, 0, 0);
            }
        }
        __syncthreads();

#pragma unroll
        for (int ks = 0; ks < 4; ++ks) {
            bf16x8 af[2], bf[2];
#pragma unroll
            for (int mi = 0; mi < 2; ++mi) {
                const int rr = wr * 32 + mi * 16 + frow;
                af[mi] = *(const bf16x8*)&Als[rr * 128 + (((ks * 4 + kq) ^ (rr & 7)) << 3)];
            }
#pragma unroll
            for (int ni = 0; ni < 2; ++ni) {
                const int rr = wc * 32 + ni * 16 + frow;
                bf[ni] = *(const bf16x8*)&Bls[rr * 128 + (((ks * 4 + kq) ^ (rr & 7)) << 3)];
            }
#pragma unroll
            for (int mi = 0; mi < 2; ++mi)
#pragma unroll
                for (int ni = 0; ni < 2; ++ni)
                    acc[mi][ni] = __builtin_amdgcn_mfma_f32_16x16x32_bf16(af[mi], bf[ni], acc[mi][ni], 0, 0, 0);
        }
        __syncthreads();
    }

#pragma unroll
    for (int ni = 0; ni < 2; ++ni) {
        const int col = n0 + wc * 32 + ni * 16 + (l & 15);
        const float bcol = bo[col];
#pragma unroll
        for (int mi = 0; mi < 2; ++mi) {
            const int rbase = m0 + wr * 32 + mi * 16 + (l >> 4) * 4;
#pragma unroll
            for (int r = 0; r < 4; ++r)
                out[(size_t)(rbase + r) * DM + col] = acc[mi][ni][r] + bcol;
        }
    }
}

// ------- Pass B: per (head, chunk) TRANSPOSED state  M^T[e][d] = sum_s V[s][e] K[s][d] -------
__global__ __launch_bounds__(256)
void chunk_state_kernel(const ushort* __restrict__ k_ws, const ushort* __restrict__ v_ws,
                        float* __restrict__ st)
{
    __shared__ float Ks[64 * 64];   // [s][d]
    __shared__ float Vs[64 * 64];   // [s][e]
    const int c = blockIdx.x, h = blockIdx.y;
    const int t = threadIdx.x;
    const ushort* Kg = k_ws + ((size_t)h * S_LEN + c * CHUNK) * DH;
    const ushort* Vg = v_ws + ((size_t)h * S_LEN + c * CHUNK) * DH;
#pragma unroll
    for (int u = 0; u < 4; ++u) {
        int f = u * 256 + t;
        const ushort4 k4 = ((const ushort4*)Kg)[f];
        const ushort4 v4 = ((const ushort4*)Vg)[f];
        float* kp = Ks + f * 4;
        float* vp = Vs + f * 4;
        kp[0] = b2f(k4.x); kp[1] = b2f(k4.y); kp[2] = b2f(k4.z); kp[3] = b2f(k4.w);
        vp[0] = b2f(v4.x); vp[1] = b2f(v4.y); vp[2] = b2f(v4.z); vp[3] = b2f(v4.w);
    }
    __syncthreads();

    const int tx = t & 15, ty = t >> 4;      // ty -> e-block, tx -> d-block (transposed)
    float acc[4][4];
#pragma unroll
    for (int i = 0; i < 4; ++i)
#pragma unroll
        for (int j = 0; j < 4; ++j) acc[i][j] = 0.0f;

    for (int s = 0; s < 64; ++s) {
        const float4 ve = *(const float4*)&Vs[s * 64 + ty * 4];
        const float4 kd = *(const float4*)&Ks[s * 64 + tx * 4];
        const float vv[4] = {ve.x, ve.y, ve.z, ve.w};
        const float kv[4] = {kd.x, kd.y, kd.z, kd.w};
#pragma unroll
        for (int i = 0; i < 4; ++i)
#pragma unroll
            for (int j = 0; j < 4; ++j) acc[i][j] += vv[i] * kv[j];
    }
    float* base = st + (size_t)(h * NCH + c) * ST_STRIDE;
#pragma unroll
    for (int i = 0; i < 4; ++i) {
        float4 o; o.x = acc[i][0]; o.y = acc[i][1]; o.z = acc[i][2]; o.w = acc[i][3];
        *(float4*)(base + (ty * 4 + i) * 64 + tx * 4) = o;   // rows = e, cols = d
    }
    if (t < 64) {
        float s = 0.0f;
        for (int j = 0; j < 64; ++j) s += Ks[j * 64 + t];
        base[DH * DH + t] = s;                               // k1[d]
    }
}

// ---- Pass C: exclusive prefix scan over chunks; bf16 copy LINEAR (coalesced) ----
__global__ __launch_bounds__(64)
void scan_kernel(float* __restrict__ st, ushort* __restrict__ pfxT)
{
    const int h = blockIdx.y;
    const int e = blockIdx.x * 64 + threadIdx.x;   // [0, ST_STRIDE)
    float* p = st + (size_t)h * NCH * ST_STRIDE + e;
    ushort* pt = pfxT + (size_t)h * NCH * ST_STRIDE + e;
    float acc = 0.0f;
    for (int c = 0; c < NCH; ++c) {
        const float v = p[(size_t)c * ST_STRIDE];
        p[(size_t)c * ST_STRIDE] = acc;            // exclusive prefix (same-thread RAW safe)
        pt[(size_t)c * ST_STRIDE] = bf16r(acc);    // coalesced
        acc += v;
    }
}

// ---------------- Pass D: per (head, chunk) output — MFMA (R11/R13-proven) ----------------
__global__ __launch_bounds__(256)
void attn_out_kernel(const ushort* __restrict__ q_ws, const ushort* __restrict__ k_ws,
                     const ushort* __restrict__ v_ws, const float* __restrict__ pfx,
                     const ushort* __restrict__ pfxT, ushort* __restrict__ out_pre)
{
    __shared__ ushort Vt[64 * 64];     // [e][s] swizzled, 8 KB
    __shared__ ushort Ps[64 * 64];     // [i][j] swizzled, 8 KB
    __shared__ float denA[64];
    __shared__ float rsA[64];

    const int c = blockIdx.x, h = blockIdx.y;
    const int t = threadIdx.x, w = t >> 6, l = t & 63;
    const int fr = l & 15, fg = l >> 4;
    const int iw0 = w * 16;                         // wave's output row stripe
    const size_t cbase = ((size_t)h * S_LEN + c * CHUNK) * DH;
    const ushort* Qg = q_ws + cbase;
    const ushort* Kg = k_ws + cbase;
    const ushort* Vg = v_ws + cbase;
    const float*  pb = pfx  + (size_t)(h * NCH + c) * ST_STRIDE;
    const ushort* pT = pfxT + (size_t)(h * NCH + c) * ST_STRIDE;

    // stage Vt = V^T (bf16, swizzled)
    {
        const int s = t >> 2, e0 = (t & 3) * 16;
        ushort vv[16];
        *(ushort4*)(vv + 0)  = *(const ushort4*)(Vg + s * 64 + e0);
        *(ushort4*)(vv + 4)  = *(const ushort4*)(Vg + s * 64 + e0 + 4);
        *(ushort4*)(vv + 8)  = *(const ushort4*)(Vg + s * 64 + e0 + 8);
        *(ushort4*)(vv + 12) = *(const ushort4*)(Vg + s * 64 + e0 + 12);
#pragma unroll
        for (int ee = 0; ee < 16; ++ee) {
            const int e = e0 + ee;
            Vt[e * 64 + ((((s >> 3) ^ (e & 7)) << 3) | (s & 7))] = vv[ee];
        }
    }

    // S = Q K^T
    bf16x8 qf[2], kf0, kf1;
#pragma unroll
    for (int kh = 0; kh < 2; ++kh)
        qf[kh] = *(const bf16x8*)(Qg + (iw0 + fr) * 64 + kh * 32 + fg * 8);

    f32x4 sacc[4];
#pragma unroll
    for (int jn = 0; jn < 4; ++jn) sacc[jn] = (f32x4){0.f, 0.f, 0.f, 0.f};
#pragma unroll
    for (int jn = 0; jn < 4; ++jn) {
        kf0 = *(const bf16x8*)(Kg + (jn * 16 + fr) * 64 + fg * 8);
        kf1 = *(const bf16x8*)(Kg + (jn * 16 + fr) * 64 + 32 + fg * 8);
        sacc[jn] = __builtin_amdgcn_mfma_f32_16x16x32_bf16(qf[0], kf0, sacc[jn], 0, 0, 0);
        sacc[jn] = __builtin_amdgcn_mfma_f32_16x16x32_bf16(qf[1], kf1, sacc[jn], 0, 0, 0);
    }

    // mask, rowsum, P -> bf16 swizzled LDS
    float pr0 = 0.f, pr1 = 0.f, pr2 = 0.f, pr3 = 0.f;
#pragma unroll
    for (int jn = 0; jn < 4; ++jn) {
        const int j = jn * 16 + fr;
        const int gj = (jn * 2 + (fr >> 3));        // granule of j
#pragma unroll
        for (int r = 0; r < 4; ++r) {
            const int i = iw0 + fg * 4 + r;
            const float v = (j <= i) ? sacc[jn][r] : 0.0f;
            if (r == 0) pr0 += v; else if (r == 1) pr1 += v;
            else if (r == 2) pr2 += v; else pr3 += v;
            Ps[i * 64 + (((gj ^ (i & 7)) << 3) | (fr & 7))] = bf16r(v);
        }
    }
#pragma unroll
    for (int d = 1; d < 16; d <<= 1) {
        pr0 += __shfl_xor(pr0, d, 64);
        pr1 += __shfl_xor(pr1, d, 64);
        pr2 += __shfl_xor(pr2, d, 64);
        pr3 += __shfl_xor(pr3, d, 64);
    }
    if (fr == 0)      rsA[iw0 + fg * 4 + 0] = pr0;
    else if (fr == 1) rsA[iw0 + fg * 4 + 1] = pr1;
    else if (fr == 2) rsA[iw0 + fg * 4 + 2] = pr2;
    else if (fr == 3) rsA[iw0 + fg * 4 + 3] = pr3;

    // den_inter = Q . k1p (fp32)
    float den = 0.f;
#pragma unroll
    for (int kh = 0; kh < 2; ++kh)
#pragma unroll
        for (int jj = 0; jj < 8; ++jj)
            den += b2f((ushort)qf[kh][jj]) * pb[DH * DH + kh * 32 + fg * 8 + jj];
    den += __shfl_xor(den, 16, 64);
    den += __shfl_xor(den, 32, 64);
    if (l < 16) denA[iw0 + l] = den;

    __syncthreads();   // Vt / Ps / denA / rsA complete

    // O = P.V + Q.KVp^T
    bf16x8 paf[2];
#pragma unroll
    for (int kh = 0; kh < 2; ++kh)
        paf[kh] = *(const bf16x8*)&Ps[(iw0 + fr) * 64 + ((((kh * 4 + fg) ^ (fr & 7))) << 3)];

    f32x4 oacc[4];
#pragma unroll
    for (int jn = 0; jn < 4; ++jn) oacc[jn] = (f32x4){0.f, 0.f, 0.f, 0.f};
#pragma unroll
    for (int jn = 0; jn < 4; ++jn) {
        const int er = jn * 16 + fr;
        const bf16x8 vt0 = *(const bf16x8*)&Vt[er * 64 + ((((0 + fg) ^ (fr & 7))) << 3)];
        const bf16x8 vt1 = *(const bf16x8*)&Vt[er * 64 + ((((4 + fg) ^ (fr & 7))) << 3)];
        const bf16x8 tf0 = *(const bf16x8*)(pT + er * 64 + fg * 8);
        const bf16x8 tf1 = *(const bf16x8*)(pT + er * 64 + 32 + fg * 8);
        oacc[jn] = __builtin_amdgcn_mfma_f32_16x16x32_bf16(paf[0], vt0, oacc[jn], 0, 0, 0);
        oacc[jn] = __builtin_amdgcn_mfma_f32_16x16x32_bf16(paf[1], vt1, oacc[jn], 0, 0, 0);
        oacc[jn] = __builtin_amdgcn_mfma_f32_16x16x32_bf16(qf[0], tf0, oacc[jn], 0, 0, 0);
        oacc[jn] = __builtin_amdgcn_mfma_f32_16x16x32_bf16(qf[1], tf1, oacc[jn], 0, 0, 0);
    }

    // epilogue: divide by den, store bf16
#pragma unroll
    for (int r = 0; r < 4; ++r) {
        const int i = iw0 + fg * 4 + r;
        const float rcp = 1.0f / (denA[i] + rsA[i]);
        const size_t rowb = (size_t)(c * CHUNK + i) * DM + h * DH;
#pragma unroll
        for (int jn = 0; jn < 4; ++jn)
            out_pre[rowb + jn * 16 + fr] = bf16r(oacc[jn][r] * rcp);
    }
}

extern "C" void kernel_launch(void* const* d_in, const int* in_sizes, int n_in,
                              void* d_out, int out_size, void* d_ws, size_t ws_size,
                              hipStream_t stream)
{
    const float* x    = (const float*)d_in[0];
    const float* Wq   = (const float*)d_in[1];
    const float* bq   = (const float*)d_in[2];
    const float* Wk   = (const float*)d_in[3];
    const float* bk   = (const float*)d_in[4];
    const float* Wv   = (const float*)d_in[5];
    const float* bv   = (const float*)d_in[6];
    const float* Wo   = (const float*)d_in[7];
    const float* bo   = (const float*)d_in[8];
    const float* beta = (const float*)d_in[9];
    float* out = (float*)d_out;

    // workspace layout
    ushort* q_ws  = (ushort*)d_ws;                                 // 3 x 2M bf16 (q|k|v)
    ushort* k_ws  = q_ws + (size_t)NH * S_LEN * DH;
    ushort* v_ws  = k_ws + (size_t)NH * S_LEN * DH;
    float*  st    = (float*)(v_ws + (size_t)NH * S_LEN * DH);      // 16*32*4160 f32
    ushort* x_bf  = (ushort*)(st + (size_t)NH * NCH * ST_STRIDE);  // 2M bf16
    ushort* w_bf  = x_bf + (size_t)S_LEN * DM;                     // 4 x 1M bf16
    ushort* op_bf = w_bf + (size_t)4 * DM * DM;                    // 2M bf16
    ushort* pfxT  = op_bf + (size_t)S_LEN * DM;                    // 16*32*4160 bf16

    const ushort* wo_bf = w_bf + (size_t)3 * DM * DM;

    cast_all_kernel<<<dim3((DM * DM) / 1024, 6), 256, 0, stream>>>(x, Wq, Wk, Wv, Wo, x_bf, w_bf);

    qkv_gemm_kernel<<<768, 256, 0, stream>>>(x_bf, w_bf, bq, bk, bv, beta, q_ws);

    chunk_state_kernel<<<dim3(NCH, NH), 256, 0, stream>>>(k_ws, v_ws, st);
    scan_kernel<<<dim3(ST_STRIDE / 64, NH), 64, 0, stream>>>(st, pfxT);
    attn_out_kernel<<<dim3(NCH, NH), 256, 0, stream>>>(q_ws, k_ws, v_ws, st, pfxT, op_bf);

    o_gemm_kernel<<<512, 256, 0, stream>>>(op_bf, wo_bf, bo, out);
}

// Round 15
// 64.202 us; speedup vs baseline: 6.1847x; 1.0161x over previous
//
#include <hip/hip_runtime.h>
#include <hip/hip_bf16.h>
#include <math.h>

#define S_LEN 2048
#define DM    1024
#define NH    16
#define DH    64
#define CHUNK 64
#define NCH   (S_LEN / CHUNK)          // 32
#define ST_STRIDE (DH * DH + DH)       // 4160 elems per (head,chunk) state

typedef __attribute__((ext_vector_type(8))) short bf16x8;   // 8 bf16 in 4 VGPRs
typedef __attribute__((ext_vector_type(4))) float f32x4;

__device__ __forceinline__ float softplus_f(float x) {
    // fast transcendentals: outputs bf16-rounded downstream (R12/R13: absmax unchanged)
    return (x > 20.0f) ? x : __logf(1.0f + __expf(x));
}

__device__ __forceinline__ ushort bf16r(float f) {   // round-to-nearest-even f32 -> bf16
    union { float f; unsigned int u; } c; c.f = f;
    unsigned int u = c.u;
    u = (u + 0x7FFFu + ((u >> 16) & 1u)) >> 16;
    return (ushort)u;
}

__device__ __forceinline__ float b2f(ushort u) {     // bf16 -> f32 (shift)
    union { unsigned int i; float f; } c; c.i = ((unsigned int)u) << 16;
    return c.f;
}

// ---------------- fused cast: x (2 slabs) + 4 weights, one launch ----------------
__global__ __launch_bounds__(256)
void cast_all_kernel(const float* __restrict__ x,
                     const float* __restrict__ Wq, const float* __restrict__ Wk,
                     const float* __restrict__ Wv, const float* __restrict__ Wo,
                     ushort* __restrict__ x_bf, ushort* __restrict__ w_bf)
{
    const int y = blockIdx.y;          // 0,1: x halves; 2..5: Wq,Wk,Wv,Wo
    const float* src;
    ushort* dst;
    if (y < 2) { src = x + (size_t)y * (DM * DM);  dst = x_bf + (size_t)y * (DM * DM); }
    else {
        const float* ws[4] = {Wq, Wk, Wv, Wo};
        src = ws[y - 2];  dst = w_bf + (size_t)(y - 2) * (DM * DM);
    }
    const int i = (blockIdx.x * 256 + threadIdx.x) * 4;
    const float4 v = *(const float4*)(src + i);
    ushort4 o; o.x = bf16r(v.x); o.y = bf16r(v.y); o.z = bf16r(v.z); o.w = bf16r(v.w);
    *(ushort4*)(dst + i) = o;
}

// ==== QKV GEMM: BM=64 x BN=128, BK=64, DOUBLE-BUFFERED counted-vmcnt, 768 blocks (3/CU) ====
// The untested quadrant: counted-vmcnt depth-2 pipeline (R6 pattern, correctness-proven) AT
// high occupancy (R8/R9's 3 blocks/CU).  LDS 2x24KB = 48KB keeps 3 blocks/CU.  Loads/wave/
// tile = 24/4 = 6 -> steady-state vmcnt(6); vmcnt(0) only on the final tile.  Inter-block
// overlap covers ds_read/MFMA latency; the pipeline removes intra-block stage serialization.
// Swizzle (verified 0-conflict): 8-row 1KB chunks; granule_phys = granule ^ (row&7);
// linear gload_lds dest + inverse-swizzled global source col (rule 21); reads same XOR.
__global__ __launch_bounds__(256)
void qkv_gemm_kernel(const ushort* __restrict__ Xb, const ushort* __restrict__ Wqkv,
                     const float* __restrict__ bq, const float* __restrict__ bk,
                     const float* __restrict__ bv,
                     const float* __restrict__ beta,
                     ushort* __restrict__ qkv /* q|k|v contiguous, bf16 head layout */)
{
    constexpr int ASZ = 64 * 64;       // ushorts per A buffer (8 KB)
    constexpr int BSZ = 128 * 64;      // ushorts per B buffer (16 KB)
    constexpr int NT  = 16;            // K tiles of 64
    __shared__ ushort Als[2 * ASZ];    // 16 KB
    __shared__ ushort Bls[2 * BSZ];    // 32 KB

    const int b = blockIdx.x;
    const int logical = (b & 7) * 96 + (b >> 3);      // XCD-bijective (768%8==0)
    const int mb = logical & 31, nb = logical >> 5;   // m-fastest within XCD
    const int m0 = mb * 64, n0 = nb * 128;
    const int z  = nb >> 3;                           // 0:q 1:k 2:v
    const int nz0 = (nb & 7) * 128;
    const float* bias = (z == 0) ? bq : (z == 1) ? bk : bv;

    const int t = threadIdx.x, w = t >> 6, l = t & 63;
    const int wr = w >> 1, wc = w & 1;                // 2x2 wave grid
    const int r8 = l >> 3;
    const int scol = ((l & 7) ^ r8) * 8;              // inverse-swizzled source col (elems)
    const int frow = l & 15, kq = l >> 4;

    f32x4 acc[2][4];
#pragma unroll
    for (int mi = 0; mi < 2; ++mi)
#pragma unroll
        for (int ni = 0; ni < 4; ++ni) acc[mi][ni] = (f32x4){0.f, 0.f, 0.f, 0.f};

    auto STAGE = [&](int buf, int kt) {               // 24 gload instrs, 6 per wave
#pragma unroll
        for (int k2 = 0; k2 < 6; ++k2) {
            const int idx = w + 4 * k2;
            if (idx < 8) {
                __builtin_amdgcn_global_load_lds(
                    (const __attribute__((address_space(1))) void*)(Xb + (size_t)(m0 + idx * 8 + r8) * DM + kt + scol),
                    (__attribute__((address_space(3))) void*)(Als + buf * ASZ + idx * 512), 16, 0, 0);
            } else {
                const int ib = idx - 8;
                __builtin_amdgcn_global_load_lds(
                    (const __attribute__((address_space(1))) void*)(Wqkv + (size_t)(n0 + ib * 8 + r8) * DM + kt + scol),
                    (__attribute__((address_space(3))) void*)(Bls + buf * BSZ + ib * 512), 16, 0, 0);
            }
        }
    };

    STAGE(0, 0);
    STAGE(1, 64);

    for (int tt = 0; tt < NT; ++tt) {
        // counted wait: this tile's 6 loads landed; next tile's 6 stay in flight
        if (tt + 1 < NT) asm volatile("s_waitcnt vmcnt(6)" ::: "memory");
        else             asm volatile("s_waitcnt vmcnt(0)" ::: "memory");
        __builtin_amdgcn_s_barrier();          // all waves' tile-tt loads landed
        asm volatile("" ::: "memory");

        const int cur = tt & 1;
        const ushort* Ab_ = Als + cur * ASZ;
        const ushort* Bb_ = Bls + cur * BSZ;
#pragma unroll
        for (int ks = 0; ks < 2; ++ks) {
            bf16x8 af[2], bf[4];
#pragma unroll
            for (int mi = 0; mi < 2; ++mi) {
                const int rr = wr * 32 + mi * 16 + frow;
                af[mi] = *(const bf16x8*)&Ab_[rr * 64 + (((kq + 4 * ks) ^ (rr & 7)) << 3)];
            }
#pragma unroll
            for (int ni = 0; ni < 4; ++ni) {
                const int rr = wc * 64 + ni * 16 + frow;
                bf[ni] = *(const bf16x8*)&Bb_[rr * 64 + (((kq + 4 * ks) ^ (rr & 7)) << 3)];
            }
#pragma unroll
            for (int mi = 0; mi < 2; ++mi)
#pragma unroll
                for (int ni = 0; ni < 4; ++ni)
                    acc[mi][ni] = __builtin_amdgcn_mfma_f32_16x16x32_bf16(af[mi], bf[ni], acc[mi][ni], 0, 0, 0);
        }

        asm volatile("" ::: "memory");         // ds_reads retired before barrier
        __builtin_amdgcn_s_barrier();          // all waves done reading buf[cur]
        asm volatile("" ::: "memory");         // STAGE stays below the barrier
        if (tt + 2 < NT) STAGE(cur, (tt + 2) * 64);
    }

    ushort* outz = qkv + (size_t)z * (NH * S_LEN * DH);
    const int hwave = (nz0 >> 6) + wc;                // wave-uniform head (2 heads per 128-col tile)
    const float inv = (z < 2) ? (1.0f / (8.0f * __expf(beta[hwave]))) : 1.0f;
#pragma unroll
    for (int ni = 0; ni < 4; ++ni) {
        const int col = nz0 + wc * 64 + ni * 16 + (l & 15);
        const int d = col & 63;
        const float bcol = bias[col];
#pragma unroll
        for (int mi = 0; mi < 2; ++mi) {
            const int rbase = m0 + wr * 32 + mi * 16 + (l >> 4) * 4;
#pragma unroll
            for (int r = 0; r < 4; ++r) {
                float v = acc[mi][ni][r] + bcol;
                if (z < 2) v = softplus_f(v * inv);
                outz[((size_t)hwave * S_LEN + rbase + r) * DH + d] = bf16r(v);
            }
        }
    }
}

// ============ O projection: LDS-staged, BK=128 -> 8 K-steps, 512 blocks (2/CU) ============
__global__ __launch_bounds__(256)
void o_gemm_kernel(const ushort* __restrict__ Ab, const ushort* __restrict__ Wob,
                   const float* __restrict__ bo, float* __restrict__ out)
{
    __shared__ ushort Als[64 * 128];    // 16 KB
    __shared__ ushort Bls[64 * 128];    // 16 KB

    const int b = blockIdx.x;
    const int logical = (b & 7) * 64 + (b >> 3);      // XCD-bijective (512%8==0)
    const int mb = logical & 31, nb = logical >> 5;   // 32 x 16 tiles
    const int m0 = mb * 64, n0 = nb * 64;

    const int t = threadIdx.x, w = t >> 6, l = t & 63;
    const int wr = w >> 1, wc = w & 1;
    const int rsub = l >> 4;
    const int frow = l & 15, kq = l >> 4;

    f32x4 acc[2][2];
#pragma unroll
    for (int mi = 0; mi < 2; ++mi)
#pragma unroll
        for (int ni = 0; ni < 2; ++ni) acc[mi][ni] = (f32x4){0.f, 0.f, 0.f, 0.f};

    for (int kt = 0; kt < DM; kt += 128) {
#pragma unroll
        for (int k2 = 0; k2 < 8; ++k2) {
            const int idx = w + 4 * k2;               // 0..31
            const int r8g = ((idx & 1) << 2) | rsub;
            const int scol = (((l & 15) ^ r8g) << 3);
            if (idx < 16) {
                __builtin_amdgcn_global_load_lds(
                    (const __attribute__((address_space(1))) void*)(Ab + (size_t)(m0 + idx * 4 + rsub) * DM + kt + scol),
                    (__attribute__((address_space(3))) void*)(Als + idx * 512), 16, 0, 0);
            } else {
                const int ib = idx - 16;
                __builtin_amdgcn_global_load_lds(
                    (const __attribute__((address_space(1))) void*)(Wob + (size_t)(n0 + ib * 4 + rsub) * DM + kt + scol),
                    (__attribute__((address_space(3))) void*)(Bls + ib * 512), 16, 0, 0);
            }
        }
        __syncthreads();

#pragma unroll
        for (int ks = 0; ks < 4; ++ks) {
            bf16x8 af[2], bf[2];
#pragma unroll
            for (int mi = 0; mi < 2; ++mi) {
                const int rr = wr * 32 + mi * 16 + frow;
                af[mi] = *(const bf16x8*)&Als[rr * 128 + (((ks * 4 + kq) ^ (rr & 7)) << 3)];
            }
#pragma unroll
            for (int ni = 0; ni < 2; ++ni) {
                const int rr = wc * 32 + ni * 16 + frow;
                bf[ni] = *(const bf16x8*)&Bls[rr * 128 + (((ks * 4 + kq) ^ (rr & 7)) << 3)];
            }
#pragma unroll
            for (int mi = 0; mi < 2; ++mi)
#pragma unroll
                for (int ni = 0; ni < 2; ++ni)
                    acc[mi][ni] = __builtin_amdgcn_mfma_f32_16x16x32_bf16(af[mi], bf[ni], acc[mi][ni], 0, 0, 0);
        }
        __syncthreads();
    }

#pragma unroll
    for (int ni = 0; ni < 2; ++ni) {
        const int col = n0 + wc * 32 + ni * 16 + (l & 15);
        const float bcol = bo[col];
#pragma unroll
        for (int mi = 0; mi < 2; ++mi) {
            const int rbase = m0 + wr * 32 + mi * 16 + (l >> 4) * 4;
#pragma unroll
            for (int r = 0; r < 4; ++r)
                out[(size_t)(rbase + r) * DM + col] = acc[mi][ni][r] + bcol;
        }
    }
}

// ------- Pass B: per (head, chunk) TRANSPOSED state  M^T[e][d] = sum_s V[s][e] K[s][d] -------
__global__ __launch_bounds__(256)
void chunk_state_kernel(const ushort* __restrict__ k_ws, const ushort* __restrict__ v_ws,
                        float* __restrict__ st)
{
    __shared__ float Ks[64 * 64];   // [s][d]
    __shared__ float Vs[64 * 64];   // [s][e]
    const int c = blockIdx.x, h = blockIdx.y;
    const int t = threadIdx.x;
    const ushort* Kg = k_ws + ((size_t)h * S_LEN + c * CHUNK) * DH;
    const ushort* Vg = v_ws + ((size_t)h * S_LEN + c * CHUNK) * DH;
#pragma unroll
    for (int u = 0; u < 4; ++u) {
        int f = u * 256 + t;
        const ushort4 k4 = ((const ushort4*)Kg)[f];
        const ushort4 v4 = ((const ushort4*)Vg)[f];
        float* kp = Ks + f * 4;
        float* vp = Vs + f * 4;
        kp[0] = b2f(k4.x); kp[1] = b2f(k4.y); kp[2] = b2f(k4.z); kp[3] = b2f(k4.w);
        vp[0] = b2f(v4.x); vp[1] = b2f(v4.y); vp[2] = b2f(v4.z); vp[3] = b2f(v4.w);
    }
    __syncthreads();

    const int tx = t & 15, ty = t >> 4;      // ty -> e-block, tx -> d-block (transposed)
    float acc[4][4];
#pragma unroll
    for (int i = 0; i < 4; ++i)
#pragma unroll
        for (int j = 0; j < 4; ++j) acc[i][j] = 0.0f;

    for (int s = 0; s < 64; ++s) {
        const float4 ve = *(const float4*)&Vs[s * 64 + ty * 4];
        const float4 kd = *(const float4*)&Ks[s * 64 + tx * 4];
        const float vv[4] = {ve.x, ve.y, ve.z, ve.w};
        const float kv[4] = {kd.x, kd.y, kd.z, kd.w};
#pragma unroll
        for (int i = 0; i < 4; ++i)
#pragma unroll
            for (int j = 0; j < 4; ++j) acc[i][j] += vv[i] * kv[j];
    }
    float* base = st + (size_t)(h * NCH + c) * ST_STRIDE;
#pragma unroll
    for (int i = 0; i < 4; ++i) {
        float4 o; o.x = acc[i][0]; o.y = acc[i][1]; o.z = acc[i][2]; o.w = acc[i][3];
        *(float4*)(base + (ty * 4 + i) * 64 + tx * 4) = o;   // rows = e, cols = d
    }
    if (t < 64) {
        float s = 0.0f;
        for (int j = 0; j < 64; ++j) s += Ks[j * 64 + t];
        base[DH * DH + t] = s;                               // k1[d]
    }
}

// ---- Pass C: exclusive prefix scan over chunks; bf16 copy LINEAR (coalesced) ----
__global__ __launch_bounds__(64)
void scan_kernel(float* __restrict__ st, ushort* __restrict__ pfxT)
{
    const int h = blockIdx.y;
    const int e = blockIdx.x * 64 + threadIdx.x;   // [0, ST_STRIDE)
    float* p = st + (size_t)h * NCH * ST_STRIDE + e;
    ushort* pt = pfxT + (size_t)h * NCH * ST_STRIDE + e;
    float acc = 0.0f;
    for (int c = 0; c < NCH; ++c) {
        const float v = p[(size_t)c * ST_STRIDE];
        p[(size_t)c * ST_STRIDE] = acc;            // exclusive prefix (same-thread RAW safe)
        pt[(size_t)c * ST_STRIDE] = bf16r(acc);    // coalesced
        acc += v;
    }
}

// ---------------- Pass D: per (head, chunk) output — MFMA (R11/R13-proven) ----------------
__global__ __launch_bounds__(256)
void attn_out_kernel(const ushort* __restrict__ q_ws, const ushort* __restrict__ k_ws,
                     const ushort* __restrict__ v_ws, const float* __restrict__ pfx,
                     const ushort* __restrict__ pfxT, ushort* __restrict__ out_pre)
{
    __shared__ ushort Vt[64 * 64];     // [e][s] swizzled, 8 KB
    __shared__ ushort Ps[64 * 64];     // [i][j] swizzled, 8 KB
    __shared__ float denA[64];
    __shared__ float rsA[64];

    const int c = blockIdx.x, h = blockIdx.y;
    const int t = threadIdx.x, w = t >> 6, l = t & 63;
    const int fr = l & 15, fg = l >> 4;
    const int iw0 = w * 16;                         // wave's output row stripe
    const size_t cbase = ((size_t)h * S_LEN + c * CHUNK) * DH;
    const ushort* Qg = q_ws + cbase;
    const ushort* Kg = k_ws + cbase;
    const ushort* Vg = v_ws + cbase;
    const float*  pb = pfx  + (size_t)(h * NCH + c) * ST_STRIDE;
    const ushort* pT = pfxT + (size_t)(h * NCH + c) * ST_STRIDE;

    // stage Vt = V^T (bf16, swizzled)
    {
        const int s = t >> 2, e0 = (t & 3) * 16;
        ushort vv[16];
        *(ushort4*)(vv + 0)  = *(const ushort4*)(Vg + s * 64 + e0);
        *(ushort4*)(vv + 4)  = *(const ushort4*)(Vg + s * 64 + e0 + 4);
        *(ushort4*)(vv + 8)  = *(const ushort4*)(Vg + s * 64 + e0 + 8);
        *(ushort4*)(vv + 12) = *(const ushort4*)(Vg + s * 64 + e0 + 12);
#pragma unroll
        for (int ee = 0; ee < 16; ++ee) {
            const int e = e0 + ee;
            Vt[e * 64 + ((((s >> 3) ^ (e & 7)) << 3) | (s & 7))] = vv[ee];
        }
    }

    // S = Q K^T
    bf16x8 qf[2], kf0, kf1;
#pragma unroll
    for (int kh = 0; kh < 2; ++kh)
        qf[kh] = *(const bf16x8*)(Qg + (iw0 + fr) * 64 + kh * 32 + fg * 8);

    f32x4 sacc[4];
#pragma unroll
    for (int jn = 0; jn < 4; ++jn) sacc[jn] = (f32x4){0.f, 0.f, 0.f, 0.f};
#pragma unroll
    for (int jn = 0; jn < 4; ++jn) {
        kf0 = *(const bf16x8*)(Kg + (jn * 16 + fr) * 64 + fg * 8);
        kf1 = *(const bf16x8*)(Kg + (jn * 16 + fr) * 64 + 32 + fg * 8);
        sacc[jn] = __builtin_amdgcn_mfma_f32_16x16x32_bf16(qf[0], kf0, sacc[jn], 0, 0, 0);
        sacc[jn] = __builtin_amdgcn_mfma_f32_16x16x32_bf16(qf[1], kf1, sacc[jn], 0, 0, 0);
    }

    // mask, rowsum, P -> bf16 swizzled LDS
    float pr0 = 0.f, pr1 = 0.f, pr2 = 0.f, pr3 = 0.f;
#pragma unroll
    for (int jn = 0; jn < 4; ++jn) {
        const int j = jn * 16 + fr;
        const int gj = (jn * 2 + (fr >> 3));        // granule of j
#pragma unroll
        for (int r = 0; r < 4; ++r) {
            const int i = iw0 + fg * 4 + r;
            const float v = (j <= i) ? sacc[jn][r] : 0.0f;
            if (r == 0) pr0 += v; else if (r == 1) pr1 += v;
            else if (r == 2) pr2 += v; else pr3 += v;
            Ps[i * 64 + (((gj ^ (i & 7)) << 3) | (fr & 7))] = bf16r(v);
        }
    }
#pragma unroll
    for (int d = 1; d < 16; d <<= 1) {
        pr0 += __shfl_xor(pr0, d, 64);
        pr1 += __shfl_xor(pr1, d, 64);
        pr2 += __shfl_xor(pr2, d, 64);
        pr3 += __shfl_xor(pr3, d, 64);
    }
    if (fr == 0)      rsA[iw0 + fg * 4 + 0] = pr0;
    else if (fr == 1) rsA[iw0 + fg * 4 + 1] = pr1;
    else if (fr == 2) rsA[iw0 + fg * 4 + 2] = pr2;
    else if (fr == 3) rsA[iw0 + fg * 4 + 3] = pr3;

    // den_inter = Q . k1p (fp32)
    float den = 0.f;
#pragma unroll
    for (int kh = 0; kh < 2; ++kh)
#pragma unroll
        for (int jj = 0; jj < 8; ++jj)
            den += b2f((ushort)qf[kh][jj]) * pb[DH * DH + kh * 32 + fg * 8 + jj];
    den += __shfl_xor(den, 16, 64);
    den += __shfl_xor(den, 32, 64);
    if (l < 16) denA[iw0 + l] = den;

    __syncthreads();   // Vt / Ps / denA / rsA complete

    // O = P.V + Q.KVp^T
    bf16x8 paf[2];
#pragma unroll
    for (int kh = 0; kh < 2; ++kh)
        paf[kh] = *(const bf16x8*)&Ps[(iw0 + fr) * 64 + ((((kh * 4 + fg) ^ (fr & 7))) << 3)];

    f32x4 oacc[4];
#pragma unroll
    for (int jn = 0; jn < 4; ++jn) oacc[jn] = (f32x4){0.f, 0.f, 0.f, 0.f};
#pragma unroll
    for (int jn = 0; jn < 4; ++jn) {
        const int er = jn * 16 + fr;
        const bf16x8 vt0 = *(const bf16x8*)&Vt[er * 64 + ((((0 + fg) ^ (fr & 7))) << 3)];
        const bf16x8 vt1 = *(const bf16x8*)&Vt[er * 64 + ((((4 + fg) ^ (fr & 7))) << 3)];
        const bf16x8 tf0 = *(const bf16x8*)(pT + er * 64 + fg * 8);
        const bf16x8 tf1 = *(const bf16x8*)(pT + er * 64 + 32 + fg * 8);
        oacc[jn] = __builtin_amdgcn_mfma_f32_16x16x32_bf16(paf[0], vt0, oacc[jn], 0, 0, 0);
        oacc[jn] = __builtin_amdgcn_mfma_f32_16x16x32_bf16(paf[1], vt1, oacc[jn], 0, 0, 0);
        oacc[jn] = __builtin_amdgcn_mfma_f32_16x16x32_bf16(qf[0], tf0, oacc[jn], 0, 0, 0);
        oacc[jn] = __builtin_amdgcn_mfma_f32_16x16x32_bf16(qf[1], tf1, oacc[jn], 0, 0, 0);
    }

    // epilogue: divide by den, store bf16
#pragma unroll
    for (int r = 0; r < 4; ++r) {
        const int i = iw0 + fg * 4 + r;
        const float rcp = 1.0f / (denA[i] + rsA[i]);
        const size_t rowb = (size_t)(c * CHUNK + i) * DM + h * DH;
#pragma unroll
        for (int jn = 0; jn < 4; ++jn)
            out_pre[rowb + jn * 16 + fr] = bf16r(oacc[jn][r] * rcp);
    }
}

extern "C" void kernel_launch(void* const* d_in, const int* in_sizes, int n_in,
                              void* d_out, int out_size, void* d_ws, size_t ws_size,
                              hipStream_t stream)
{
    const float* x    = (const float*)d_in[0];
    const float* Wq   = (const float*)d_in[1];
    const float* bq   = (const float*)d_in[2];
    const float* Wk   = (const float*)d_in[3];
    const float* bk   = (const float*)d_in[4];
    const float* Wv   = (const float*)d_in[5];
    const float* bv   = (const float*)d_in[6];
    const float* Wo   = (const float*)d_in[7];
    const float* bo   = (const float*)d_in[8];
    const float* beta = (const float*)d_in[9];
    float* out = (float*)d_out;

    // workspace layout
    ushort* q_ws  = (ushort*)d_ws;                                 // 3 x 2M bf16 (q|k|v)
    ushort* k_ws  = q_ws + (size_t)NH * S_LEN * DH;
    ushort* v_ws  = k_ws + (size_t)NH * S_LEN * DH;
    float*  st    = (float*)(v_ws + (size_t)NH * S_LEN * DH);      // 16*32*4160 f32
    ushort* x_bf  = (ushort*)(st + (size_t)NH * NCH * ST_STRIDE);  // 2M bf16
    ushort* w_bf  = x_bf + (size_t)S_LEN * DM;                     // 4 x 1M bf16
    ushort* op_bf = w_bf + (size_t)4 * DM * DM;                    // 2M bf16
    ushort* pfxT  = op_bf + (size_t)S_LEN * DM;                    // 16*32*4160 bf16

    const ushort* wo_bf = w_bf + (size_t)3 * DM * DM;

    cast_all_kernel<<<dim3((DM * DM) / 1024, 6), 256, 0, stream>>>(x, Wq, Wk, Wv, Wo, x_bf, w_bf);

    qkv_gemm_kernel<<<768, 256, 0, stream>>>(x_bf, w_bf, bq, bk, bv, beta, q_ws);

    chunk_state_kernel<<<dim3(NCH, NH), 256, 0, stream>>>(k_ws, v_ws, st);
    scan_kernel<<<dim3(ST_STRIDE / 64, NH), 64, 0, stream>>>(st, pfxT);
    attn_out_kernel<<<dim3(NCH, NH), 256, 0, stream>>>(q_ws, k_ws, v_ws, st, pfxT, op_bf);

    o_gemm_kernel<<<512, 256, 0, stream>>>(op_bf, wo_bf, bo, out);
}

// Round 16
// 62.002 us; speedup vs baseline: 6.4041x; 1.0355x over previous
//
#include <hip/hip_runtime.h>
#include <hip/hip_bf16.h>
#include <math.h>

#define S_LEN 2048
#define DM    1024
#define NH    16
#define DH    64
#define CHUNK 64
#define NCH   (S_LEN / CHUNK)          // 32
#define ST_STRIDE (DH * DH + DH)       // 4160 elems per (head,chunk) state

typedef __attribute__((ext_vector_type(8))) short bf16x8;   // 8 bf16 in 4 VGPRs
typedef __attribute__((ext_vector_type(4))) float f32x4;

__device__ __forceinline__ float softplus_f(float x) {
    // fast transcendentals: outputs bf16-rounded downstream (R12/R13: absmax unchanged)
    return (x > 20.0f) ? x : __logf(1.0f + __expf(x));
}

__device__ __forceinline__ ushort bf16r(float f) {   // round-to-nearest-even f32 -> bf16
    union { float f; unsigned int u; } c; c.f = f;
    unsigned int u = c.u;
    u = (u + 0x7FFFu + ((u >> 16) & 1u)) >> 16;
    return (ushort)u;
}

__device__ __forceinline__ float b2f(ushort u) {     // bf16 -> f32 (shift)
    union { unsigned int i; float f; } c; c.i = ((unsigned int)u) << 16;
    return c.f;
}

// ---------------- fused cast: x (2 slabs) + 4 weights, one launch ----------------
__global__ __launch_bounds__(256)
void cast_all_kernel(const float* __restrict__ x,
                     const float* __restrict__ Wq, const float* __restrict__ Wk,
                     const float* __restrict__ Wv, const float* __restrict__ Wo,
                     ushort* __restrict__ x_bf, ushort* __restrict__ w_bf)
{
    const int y = blockIdx.y;          // 0,1: x halves; 2..5: Wq,Wk,Wv,Wo
    const float* src;
    ushort* dst;
    if (y < 2) { src = x + (size_t)y * (DM * DM);  dst = x_bf + (size_t)y * (DM * DM); }
    else {
        const float* ws[4] = {Wq, Wk, Wv, Wo};
        src = ws[y - 2];  dst = w_bf + (size_t)(y - 2) * (DM * DM);
    }
    const int i = (blockIdx.x * 256 + threadIdx.x) * 4;
    const float4 v = *(const float4*)(src + i);
    ushort4 o; o.x = bf16r(v.x); o.y = bf16r(v.y); o.z = bf16r(v.z); o.w = bf16r(v.w);
    *(ushort4*)(dst + i) = o;
}

// ==== QKV GEMM: BM=64 x BN=128, BK=64, DOUBLE-BUFFERED counted-vmcnt, 768 blocks (3/CU) ====
// R15-proven.  Swizzle: 8-row 1KB chunks; granule_phys = granule ^ (row&7); linear
// gload_lds dest + inverse-swizzled global source col (rule 21); reads same XOR.
__global__ __launch_bounds__(256)
void qkv_gemm_kernel(const ushort* __restrict__ Xb, const ushort* __restrict__ Wqkv,
                     const float* __restrict__ bq, const float* __restrict__ bk,
                     const float* __restrict__ bv,
                     const float* __restrict__ beta,
                     ushort* __restrict__ qkv /* q|k|v contiguous, bf16 head layout */)
{
    constexpr int ASZ = 64 * 64;       // ushorts per A buffer (8 KB)
    constexpr int BSZ = 128 * 64;      // ushorts per B buffer (16 KB)
    constexpr int NT  = 16;            // K tiles of 64
    __shared__ ushort Als[2 * ASZ];    // 16 KB
    __shared__ ushort Bls[2 * BSZ];    // 32 KB

    const int b = blockIdx.x;
    const int logical = (b & 7) * 96 + (b >> 3);      // XCD-bijective (768%8==0)
    const int mb = logical & 31, nb = logical >> 5;   // m-fastest within XCD
    const int m0 = mb * 64, n0 = nb * 128;
    const int z  = nb >> 3;                           // 0:q 1:k 2:v
    const int nz0 = (nb & 7) * 128;
    const float* bias = (z == 0) ? bq : (z == 1) ? bk : bv;

    const int t = threadIdx.x, w = t >> 6, l = t & 63;
    const int wr = w >> 1, wc = w & 1;                // 2x2 wave grid
    const int r8 = l >> 3;
    const int scol = ((l & 7) ^ r8) * 8;              // inverse-swizzled source col (elems)
    const int frow = l & 15, kq = l >> 4;

    f32x4 acc[2][4];
#pragma unroll
    for (int mi = 0; mi < 2; ++mi)
#pragma unroll
        for (int ni = 0; ni < 4; ++ni) acc[mi][ni] = (f32x4){0.f, 0.f, 0.f, 0.f};

    auto STAGE = [&](int buf, int kt) {               // 24 gload instrs, 6 per wave
#pragma unroll
        for (int k2 = 0; k2 < 6; ++k2) {
            const int idx = w + 4 * k2;
            if (idx < 8) {
                __builtin_amdgcn_global_load_lds(
                    (const __attribute__((address_space(1))) void*)(Xb + (size_t)(m0 + idx * 8 + r8) * DM + kt + scol),
                    (__attribute__((address_space(3))) void*)(Als + buf * ASZ + idx * 512), 16, 0, 0);
            } else {
                const int ib = idx - 8;
                __builtin_amdgcn_global_load_lds(
                    (const __attribute__((address_space(1))) void*)(Wqkv + (size_t)(n0 + ib * 8 + r8) * DM + kt + scol),
                    (__attribute__((address_space(3))) void*)(Bls + buf * BSZ + ib * 512), 16, 0, 0);
            }
        }
    };

    STAGE(0, 0);
    STAGE(1, 64);

    for (int tt = 0; tt < NT; ++tt) {
        // counted wait: this tile's 6 loads landed; next tile's 6 stay in flight
        if (tt + 1 < NT) asm volatile("s_waitcnt vmcnt(6)" ::: "memory");
        else             asm volatile("s_waitcnt vmcnt(0)" ::: "memory");
        __builtin_amdgcn_s_barrier();          // all waves' tile-tt loads landed
        asm volatile("" ::: "memory");

        const int cur = tt & 1;
        const ushort* Ab_ = Als + cur * ASZ;
        const ushort* Bb_ = Bls + cur * BSZ;
#pragma unroll
        for (int ks = 0; ks < 2; ++ks) {
            bf16x8 af[2], bf[4];
#pragma unroll
            for (int mi = 0; mi < 2; ++mi) {
                const int rr = wr * 32 + mi * 16 + frow;
                af[mi] = *(const bf16x8*)&Ab_[rr * 64 + (((kq + 4 * ks) ^ (rr & 7)) << 3)];
            }
#pragma unroll
            for (int ni = 0; ni < 4; ++ni) {
                const int rr = wc * 64 + ni * 16 + frow;
                bf[ni] = *(const bf16x8*)&Bb_[rr * 64 + (((kq + 4 * ks) ^ (rr & 7)) << 3)];
            }
#pragma unroll
            for (int mi = 0; mi < 2; ++mi)
#pragma unroll
                for (int ni = 0; ni < 4; ++ni)
                    acc[mi][ni] = __builtin_amdgcn_mfma_f32_16x16x32_bf16(af[mi], bf[ni], acc[mi][ni], 0, 0, 0);
        }

        asm volatile("" ::: "memory");         // ds_reads retired before barrier
        __builtin_amdgcn_s_barrier();          // all waves done reading buf[cur]
        asm volatile("" ::: "memory");         // STAGE stays below the barrier
        if (tt + 2 < NT) STAGE(cur, (tt + 2) * 64);
    }

    ushort* outz = qkv + (size_t)z * (NH * S_LEN * DH);
    const int hwave = (nz0 >> 6) + wc;                // wave-uniform head (2 heads per 128-col tile)
    const float inv = (z < 2) ? (1.0f / (8.0f * __expf(beta[hwave]))) : 1.0f;
#pragma unroll
    for (int ni = 0; ni < 4; ++ni) {
        const int col = nz0 + wc * 64 + ni * 16 + (l & 15);
        const int d = col & 63;
        const float bcol = bias[col];
#pragma unroll
        for (int mi = 0; mi < 2; ++mi) {
            const int rbase = m0 + wr * 32 + mi * 16 + (l >> 4) * 4;
#pragma unroll
            for (int r = 0; r < 4; ++r) {
                float v = acc[mi][ni][r] + bcol;
                if (z < 2) v = softplus_f(v * inv);
                outz[((size_t)hwave * S_LEN + rbase + r) * DH + d] = bf16r(v);
            }
        }
    }
}

// ============ O projection: LDS-staged, BK=128 -> 8 K-steps, 512 blocks (2/CU) ============
__global__ __launch_bounds__(256)
void o_gemm_kernel(const ushort* __restrict__ Ab, const ushort* __restrict__ Wob,
                   const float* __restrict__ bo, float* __restrict__ out)
{
    __shared__ ushort Als[64 * 128];    // 16 KB
    __shared__ ushort Bls[64 * 128];    // 16 KB

    const int b = blockIdx.x;
    const int logical = (b & 7) * 64 + (b >> 3);      // XCD-bijective (512%8==0)
    const int mb = logical & 31, nb = logical >> 5;   // 32 x 16 tiles
    const int m0 = mb * 64, n0 = nb * 64;

    const int t = threadIdx.x, w = t >> 6, l = t & 63;
    const int wr = w >> 1, wc = w & 1;
    const int rsub = l >> 4;
    const int frow = l & 15, kq = l >> 4;

    f32x4 acc[2][2];
#pragma unroll
    for (int mi = 0; mi < 2; ++mi)
#pragma unroll
        for (int ni = 0; ni < 2; ++ni) acc[mi][ni] = (f32x4){0.f, 0.f, 0.f, 0.f};

    for (int kt = 0; kt < DM; kt += 128) {
#pragma unroll
        for (int k2 = 0; k2 < 8; ++k2) {
            const int idx = w + 4 * k2;               // 0..31
            const int r8g = ((idx & 1) << 2) | rsub;
            const int scol = (((l & 15) ^ r8g) << 3);
            if (idx < 16) {
                __builtin_amdgcn_global_load_lds(
                    (const __attribute__((address_space(1))) void*)(Ab + (size_t)(m0 + idx * 4 + rsub) * DM + kt + scol),
                    (__attribute__((address_space(3))) void*)(Als + idx * 512), 16, 0, 0);
            } else {
                const int ib = idx - 16;
                __builtin_amdgcn_global_load_lds(
                    (const __attribute__((address_space(1))) void*)(Wob + (size_t)(n0 + ib * 4 + rsub) * DM + kt + scol),
                    (__attribute__((address_space(3))) void*)(Bls + ib * 512), 16, 0, 0);
            }
        }
        __syncthreads();

#pragma unroll
        for (int ks = 0; ks < 4; ++ks) {
            bf16x8 af[2], bf[2];
#pragma unroll
            for (int mi = 0; mi < 2; ++mi) {
                const int rr = wr * 32 + mi * 16 + frow;
                af[mi] = *(const bf16x8*)&Als[rr * 128 + (((ks * 4 + kq) ^ (rr & 7)) << 3)];
            }
#pragma unroll
            for (int ni = 0; ni < 2; ++ni) {
                const int rr = wc * 32 + ni * 16 + frow;
                bf[ni] = *(const bf16x8*)&Bls[rr * 128 + (((ks * 4 + kq) ^ (rr & 7)) << 3)];
            }
#pragma unroll
            for (int mi = 0; mi < 2; ++mi)
#pragma unroll
                for (int ni = 0; ni < 2; ++ni)
                    acc[mi][ni] = __builtin_amdgcn_mfma_f32_16x16x32_bf16(af[mi], bf[ni], acc[mi][ni], 0, 0, 0);
        }
        __syncthreads();
    }

#pragma unroll
    for (int ni = 0; ni < 2; ++ni) {
        const int col = n0 + wc * 32 + ni * 16 + (l & 15);
        const float bcol = bo[col];
#pragma unroll
        for (int mi = 0; mi < 2; ++mi) {
            const int rbase = m0 + wr * 32 + mi * 16 + (l >> 4) * 4;
#pragma unroll
            for (int r = 0; r < 4; ++r)
                out[(size_t)(rbase + r) * DM + col] = acc[mi][ni][r] + bcol;
        }
    }
}

// ------- Pass B: TRANSPOSED chunk state via MFMA  M^T[e][d] = sum_s V[s][e] K[s][d] -------
// A-operand = V^T rows (e,s-contig), B-operand = K^T rows (d,s-contig): both staged bf16
// with the attn-proven transpose+swizzle (granule_phys = granule ^ (row&7)).  8 MFMA/wave.
// k1[d] = column sum of K read from global (L1-hot, coalesced across lanes).
__global__ __launch_bounds__(256)
void chunk_state_kernel(const ushort* __restrict__ k_ws, const ushort* __restrict__ v_ws,
                        float* __restrict__ st)
{
    __shared__ ushort Kt[64 * 64];   // [d][s] swizzled, 8 KB
    __shared__ ushort Vt[64 * 64];   // [e][s] swizzled, 8 KB

    const int c = blockIdx.x, h = blockIdx.y;
    const int t = threadIdx.x, w = t >> 6, l = t & 63;
    const int fr = l & 15, fg = l >> 4;
    const int iw0 = w * 16;                          // wave's e-row stripe
    const ushort* Kg = k_ws + ((size_t)h * S_LEN + c * CHUNK) * DH;
    const ushort* Vg = v_ws + ((size_t)h * S_LEN + c * CHUNK) * DH;

    // stage K^T and V^T (bf16, swizzled) — thread t: source row s = t>>2, 16-col block
    {
        const int s = t >> 2, e0 = (t & 3) * 16;
        ushort kk[16], vv[16];
        *(ushort4*)(kk + 0)  = *(const ushort4*)(Kg + s * 64 + e0);
        *(ushort4*)(kk + 4)  = *(const ushort4*)(Kg + s * 64 + e0 + 4);
        *(ushort4*)(kk + 8)  = *(const ushort4*)(Kg + s * 64 + e0 + 8);
        *(ushort4*)(kk + 12) = *(const ushort4*)(Kg + s * 64 + e0 + 12);
        *(ushort4*)(vv + 0)  = *(const ushort4*)(Vg + s * 64 + e0);
        *(ushort4*)(vv + 4)  = *(const ushort4*)(Vg + s * 64 + e0 + 4);
        *(ushort4*)(vv + 8)  = *(const ushort4*)(Vg + s * 64 + e0 + 8);
        *(ushort4*)(vv + 12) = *(const ushort4*)(Vg + s * 64 + e0 + 12);
#pragma unroll
        for (int ee = 0; ee < 16; ++ee) {
            const int e = e0 + ee;
            const int slot = ((((s >> 3) ^ (e & 7)) << 3) | (s & 7));
            Kt[e * 64 + slot] = kk[ee];
            Vt[e * 64 + slot] = vv[ee];
        }
    }
    __syncthreads();

    // M^T[e][d]: A-frag from Vt (row e), B-frag from Kt (row d); accumulate over 2 k-halves
    f32x4 macc[4];
#pragma unroll
    for (int jn = 0; jn < 4; ++jn) macc[jn] = (f32x4){0.f, 0.f, 0.f, 0.f};
    bf16x8 vf[2];
#pragma unroll
    for (int kh = 0; kh < 2; ++kh) {
        const int er = iw0 + fr;
        vf[kh] = *(const bf16x8*)&Vt[er * 64 + ((((kh * 4 + fg) ^ (er & 7))) << 3)];
    }
#pragma unroll
    for (int jn = 0; jn < 4; ++jn) {
        const int dr = jn * 16 + fr;
        const bf16x8 kf0 = *(const bf16x8*)&Kt[dr * 64 + ((((0 + fg) ^ (dr & 7))) << 3)];
        const bf16x8 kf1 = *(const bf16x8*)&Kt[dr * 64 + ((((4 + fg) ^ (dr & 7))) << 3)];
        macc[jn] = __builtin_amdgcn_mfma_f32_16x16x32_bf16(vf[0], kf0, macc[jn], 0, 0, 0);
        macc[jn] = __builtin_amdgcn_mfma_f32_16x16x32_bf16(vf[1], kf1, macc[jn], 0, 0, 0);
    }

    float* base = st + (size_t)(h * NCH + c) * ST_STRIDE;
#pragma unroll
    for (int jn = 0; jn < 4; ++jn) {
        const int d = jn * 16 + (l & 15);
#pragma unroll
        for (int r = 0; r < 4; ++r) {
            const int e = iw0 + fg * 4 + r;
            base[e * 64 + d] = macc[jn][r];          // rows = e, cols = d
        }
    }
    // k1[d] = sum_s K[s][d] — global column sum, lanes coalesced per iteration
    if (t < 64) {
        float s = 0.0f;
        for (int j = 0; j < 64; ++j) s += b2f(Kg[j * 64 + t]);
        base[DH * DH + t] = s;
    }
}

// ---- Pass C: exclusive prefix scan over chunks; bf16 copy LINEAR (coalesced) ----
__global__ __launch_bounds__(64)
void scan_kernel(float* __restrict__ st, ushort* __restrict__ pfxT)
{
    const int h = blockIdx.y;
    const int e = blockIdx.x * 64 + threadIdx.x;   // [0, ST_STRIDE)
    float* p = st + (size_t)h * NCH * ST_STRIDE + e;
    ushort* pt = pfxT + (size_t)h * NCH * ST_STRIDE + e;
    float acc = 0.0f;
    for (int c = 0; c < NCH; ++c) {
        const float v = p[(size_t)c * ST_STRIDE];
        p[(size_t)c * ST_STRIDE] = acc;            // exclusive prefix (same-thread RAW safe)
        pt[(size_t)c * ST_STRIDE] = bf16r(acc);    // coalesced
        acc += v;
    }
}

// ---------------- Pass D: per (head, chunk) output — MFMA (R11/R13-proven) ----------------
__global__ __launch_bounds__(256)
void attn_out_kernel(const ushort* __restrict__ q_ws, const ushort* __restrict__ k_ws,
                     const ushort* __restrict__ v_ws, const float* __restrict__ pfx,
                     const ushort* __restrict__ pfxT, ushort* __restrict__ out_pre)
{
    __shared__ ushort Vt[64 * 64];     // [e][s] swizzled, 8 KB
    __shared__ ushort Ps[64 * 64];     // [i][j] swizzled, 8 KB
    __shared__ float denA[64];
    __shared__ float rsA[64];

    const int c = blockIdx.x, h = blockIdx.y;
    const int t = threadIdx.x, w = t >> 6, l = t & 63;
    const int fr = l & 15, fg = l >> 4;
    const int iw0 = w * 16;                         // wave's output row stripe
    const size_t cbase = ((size_t)h * S_LEN + c * CHUNK) * DH;
    const ushort* Qg = q_ws + cbase;
    const ushort* Kg = k_ws + cbase;
    const ushort* Vg = v_ws + cbase;
    const float*  pb = pfx  + (size_t)(h * NCH + c) * ST_STRIDE;
    const ushort* pT = pfxT + (size_t)(h * NCH + c) * ST_STRIDE;

    // stage Vt = V^T (bf16, swizzled)
    {
        const int s = t >> 2, e0 = (t & 3) * 16;
        ushort vv[16];
        *(ushort4*)(vv + 0)  = *(const ushort4*)(Vg + s * 64 + e0);
        *(ushort4*)(vv + 4)  = *(const ushort4*)(Vg + s * 64 + e0 + 4);
        *(ushort4*)(vv + 8)  = *(const ushort4*)(Vg + s * 64 + e0 + 8);
        *(ushort4*)(vv + 12) = *(const ushort4*)(Vg + s * 64 + e0 + 12);
#pragma unroll
        for (int ee = 0; ee < 16; ++ee) {
            const int e = e0 + ee;
            Vt[e * 64 + ((((s >> 3) ^ (e & 7)) << 3) | (s & 7))] = vv[ee];
        }
    }

    // S = Q K^T
    bf16x8 qf[2], kf0, kf1;
#pragma unroll
    for (int kh = 0; kh < 2; ++kh)
        qf[kh] = *(const bf16x8*)(Qg + (iw0 + fr) * 64 + kh * 32 + fg * 8);

    f32x4 sacc[4];
#pragma unroll
    for (int jn = 0; jn < 4; ++jn) sacc[jn] = (f32x4){0.f, 0.f, 0.f, 0.f};
#pragma unroll
    for (int jn = 0; jn < 4; ++jn) {
        kf0 = *(const bf16x8*)(Kg + (jn * 16 + fr) * 64 + fg * 8);
        kf1 = *(const bf16x8*)(Kg + (jn * 16 + fr) * 64 + 32 + fg * 8);
        sacc[jn] = __builtin_amdgcn_mfma_f32_16x16x32_bf16(qf[0], kf0, sacc[jn], 0, 0, 0);
        sacc[jn] = __builtin_amdgcn_mfma_f32_16x16x32_bf16(qf[1], kf1, sacc[jn], 0, 0, 0);
    }

    // mask, rowsum, P -> bf16 swizzled LDS
    float pr0 = 0.f, pr1 = 0.f, pr2 = 0.f, pr3 = 0.f;
#pragma unroll
    for (int jn = 0; jn < 4; ++jn) {
        const int j = jn * 16 + fr;
        const int gj = (jn * 2 + (fr >> 3));        // granule of j
#pragma unroll
        for (int r = 0; r < 4; ++r) {
            const int i = iw0 + fg * 4 + r;
            const float v = (j <= i) ? sacc[jn][r] : 0.0f;
            if (r == 0) pr0 += v; else if (r == 1) pr1 += v;
            else if (r == 2) pr2 += v; else pr3 += v;
            Ps[i * 64 + (((gj ^ (i & 7)) << 3) | (fr & 7))] = bf16r(v);
        }
    }
#pragma unroll
    for (int d = 1; d < 16; d <<= 1) {
        pr0 += __shfl_xor(pr0, d, 64);
        pr1 += __shfl_xor(pr1, d, 64);
        pr2 += __shfl_xor(pr2, d, 64);
        pr3 += __shfl_xor(pr3, d, 64);
    }
    if (fr == 0)      rsA[iw0 + fg * 4 + 0] = pr0;
    else if (fr == 1) rsA[iw0 + fg * 4 + 1] = pr1;
    else if (fr == 2) rsA[iw0 + fg * 4 + 2] = pr2;
    else if (fr == 3) rsA[iw0 + fg * 4 + 3] = pr3;

    // den_inter = Q . k1p (fp32)
    float den = 0.f;
#pragma unroll
    for (int kh = 0; kh < 2; ++kh)
#pragma unroll
        for (int jj = 0; jj < 8; ++jj)
            den += b2f((ushort)qf[kh][jj]) * pb[DH * DH + kh * 32 + fg * 8 + jj];
    den += __shfl_xor(den, 16, 64);
    den += __shfl_xor(den, 32, 64);
    if (l < 16) denA[iw0 + l] = den;

    __syncthreads();   // Vt / Ps / denA / rsA complete

    // O = P.V + Q.KVp^T
    bf16x8 paf[2];
#pragma unroll
    for (int kh = 0; kh < 2; ++kh)
        paf[kh] = *(const bf16x8*)&Ps[(iw0 + fr) * 64 + ((((kh * 4 + fg) ^ (fr & 7))) << 3)];

    f32x4 oacc[4];
#pragma unroll
    for (int jn = 0; jn < 4; ++jn) oacc[jn] = (f32x4){0.f, 0.f, 0.f, 0.f};
#pragma unroll
    for (int jn = 0; jn < 4; ++jn) {
        const int er = jn * 16 + fr;
        const bf16x8 vt0 = *(const bf16x8*)&Vt[er * 64 + ((((0 + fg) ^ (fr & 7))) << 3)];
        const bf16x8 vt1 = *(const bf16x8*)&Vt[er * 64 + ((((4 + fg) ^ (fr & 7))) << 3)];
        const bf16x8 tf0 = *(const bf16x8*)(pT + er * 64 + fg * 8);
        const bf16x8 tf1 = *(const bf16x8*)(pT + er * 64 + 32 + fg * 8);
        oacc[jn] = __builtin_amdgcn_mfma_f32_16x16x32_bf16(paf[0], vt0, oacc[jn], 0, 0, 0);
        oacc[jn] = __builtin_amdgcn_mfma_f32_16x16x32_bf16(paf[1], vt1, oacc[jn], 0, 0, 0);
        oacc[jn] = __builtin_amdgcn_mfma_f32_16x16x32_bf16(qf[0], tf0, oacc[jn], 0, 0, 0);
        oacc[jn] = __builtin_amdgcn_mfma_f32_16x16x32_bf16(qf[1], tf1, oacc[jn], 0, 0, 0);
    }

    // epilogue: divide by den, store bf16
#pragma unroll
    for (int r = 0; r < 4; ++r) {
        const int i = iw0 + fg * 4 + r;
        const float rcp = 1.0f / (denA[i] + rsA[i]);
        const size_t rowb = (size_t)(c * CHUNK + i) * DM + h * DH;
#pragma unroll
        for (int jn = 0; jn < 4; ++jn)
            out_pre[rowb + jn * 16 + fr] = bf16r(oacc[jn][r] * rcp);
    }
}

extern "C" void kernel_launch(void* const* d_in, const int* in_sizes, int n_in,
                              void* d_out, int out_size, void* d_ws, size_t ws_size,
                              hipStream_t stream)
{
    const float* x    = (const float*)d_in[0];
    const float* Wq   = (const float*)d_in[1];
    const float* bq   = (const float*)d_in[2];
    const float* Wk   = (const float*)d_in[3];
    const float* bk   = (const float*)d_in[4];
    const float* Wv   = (const float*)d_in[5];
    const float* bv   = (const float*)d_in[6];
    const float* Wo   = (const float*)d_in[7];
    const float* bo   = (const float*)d_in[8];
    const float* beta = (const float*)d_in[9];
    float* out = (float*)d_out;

    // workspace layout
    ushort* q_ws  = (ushort*)d_ws;                                 // 3 x 2M bf16 (q|k|v)
    ushort* k_ws  = q_ws + (size_t)NH * S_LEN * DH;
    ushort* v_ws  = k_ws + (size_t)NH * S_LEN * DH;
    float*  st    = (float*)(v_ws + (size_t)NH * S_LEN * DH);      // 16*32*4160 f32
    ushort* x_bf  = (ushort*)(st + (size_t)NH * NCH * ST_STRIDE);  // 2M bf16
    ushort* w_bf  = x_bf + (size_t)S_LEN * DM;                     // 4 x 1M bf16
    ushort* op_bf = w_bf + (size_t)4 * DM * DM;                    // 2M bf16
    ushort* pfxT  = op_bf + (size_t)S_LEN * DM;                    // 16*32*4160 bf16

    const ushort* wo_bf = w_bf + (size_t)3 * DM * DM;

    cast_all_kernel<<<dim3((DM * DM) / 1024, 6), 256, 0, stream>>>(x, Wq, Wk, Wv, Wo, x_bf, w_bf);

    qkv_gemm_kernel<<<768, 256, 0, stream>>>(x_bf, w_bf, bq, bk, bv, beta, q_ws);

    chunk_state_kernel<<<dim3(NCH, NH), 256, 0, stream>>>(k_ws, v_ws, st);
    scan_kernel<<<dim3(ST_STRIDE / 64, NH), 64, 0, stream>>>(st, pfxT);
    attn_out_kernel<<<dim3(NCH, NH), 256, 0, stream>>>(q_ws, k_ws, v_ws, st, pfxT, op_bf);

    o_gemm_kernel<<<512, 256, 0, stream>>>(op_bf, wo_bf, bo, out);
}